// Round 5
// baseline (670.980 us; speedup 1.0000x reference)
//
#include <hip/hip_runtime.h>
#include <hip/hip_bf16.h>

#define FIN   128
#define HEADS 4
#define HID   32
#define NCLS  40
#define NEG_SLOPE 0.2f

typedef __bf16 bf16x8 __attribute__((ext_vector_type(8)));
typedef float  f32x4  __attribute__((ext_vector_type(4)));

__device__ inline unsigned short bf16_rne(float f) {
    unsigned u = __float_as_uint(f);
    return (unsigned short)((u + 0x7fffu + ((u >> 16) & 1u)) >> 16);
}
__device__ inline float bf16_to_f(unsigned short h) {
    return __uint_as_float(((unsigned)h) << 16);
}

// ===== pack W[k,col] fp32 -> B-fragment-ordered bf16 hi/lo planes ===========
template<int NC>
__global__ void packW_k(const float* __restrict__ W, unsigned short* __restrict__ Bhi,
                        unsigned short* __restrict__ Blo, int NO) {
    int idx = blockIdx.x * 256 + threadIdx.x;
    int total = 4 * NC * 64 * 8;
    if (idx >= total) return;
    int i = idx & 7;
    int rest = idx >> 3;
    int l = rest & 63;
    int rest2 = rest >> 6;
    int c = rest2 % NC;
    int t = rest2 / NC;
    int k   = t * 32 + (l >> 4) * 8 + i;
    int col = c * 16 + (l & 15);
    float val = (col < NO) ? W[(size_t)k * NO + col] : 0.f;
    unsigned short hi = bf16_rne(val);
    unsigned short lo = bf16_rne(val - bf16_to_f(hi));
    Bhi[idx] = hi;
    Blo[idx] = lo;
}

// ===== MFMA GEMM: Y[n,NO] = X[n,128] @ W[128,NO], split-bf16 ================
template<int NC>
__global__ __launch_bounds__(256) void gemm_mfma_k(
        const float* __restrict__ X, const unsigned short* __restrict__ Bhi,
        const unsigned short* __restrict__ Blo, float* __restrict__ Y,
        int n, int NO) {
    int wave = threadIdx.x >> 6;
    int lane = threadIdx.x & 63;
    int rowbase = (blockIdx.x * 4 + wave) * 32;
    if (rowbase >= n) return;
    int r0 = lane & 15, kg = lane >> 4;

    f32x4 acc[2][NC];
#pragma unroll
    for (int rt = 0; rt < 2; ++rt)
#pragma unroll
        for (int c = 0; c < NC; ++c) acc[rt][c] = f32x4{0.f, 0.f, 0.f, 0.f};

    for (int t = 0; t < 4; ++t) {
        union U { unsigned short u[8]; bf16x8 v; };
        U ah[2], al[2];
#pragma unroll
        for (int rt = 0; rt < 2; ++rt) {
            int row = min(rowbase + rt * 16 + r0, n - 1);
            const float* xp = X + (size_t)row * 128 + t * 32 + kg * 8;
            float4 xa = *reinterpret_cast<const float4*>(xp);
            float4 xb = *reinterpret_cast<const float4*>(xp + 4);
            float f[8] = {xa.x, xa.y, xa.z, xa.w, xb.x, xb.y, xb.z, xb.w};
#pragma unroll
            for (int i = 0; i < 8; ++i) {
                unsigned short h = bf16_rne(f[i]);
                ah[rt].u[i] = h;
                al[rt].u[i] = bf16_rne(f[i] - bf16_to_f(h));
            }
        }
#pragma unroll
        for (int c = 0; c < NC; ++c) {
            size_t boff = (((size_t)t * NC + c) * 64 + lane) * 8;
            bf16x8 bh = *reinterpret_cast<const bf16x8*>(Bhi + boff);
            bf16x8 bl = *reinterpret_cast<const bf16x8*>(Blo + boff);
#pragma unroll
            for (int rt = 0; rt < 2; ++rt) {
                acc[rt][c] = __builtin_amdgcn_mfma_f32_16x16x32_bf16(ah[rt].v, bh, acc[rt][c], 0, 0, 0);
                acc[rt][c] = __builtin_amdgcn_mfma_f32_16x16x32_bf16(al[rt].v, bh, acc[rt][c], 0, 0, 0);
                acc[rt][c] = __builtin_amdgcn_mfma_f32_16x16x32_bf16(ah[rt].v, bl, acc[rt][c], 0, 0, 0);
            }
        }
    }

#pragma unroll
    for (int rt = 0; rt < 2; ++rt)
#pragma unroll
        for (int c = 0; c < NC; ++c)
#pragma unroll
            for (int r = 0; r < 4; ++r) {
                int row = rowbase + rt * 16 + kg * 4 + r;
                int col = c * 16 + r0;
                if (row < n && col < NO)
                    Y[(size_t)row * NO + col] = acc[rt][c][r];
            }
}

// ===== attention logits per node (float4) ===================================
__global__ void scores_k(const float* __restrict__ H, const float* __restrict__ asrc,
                         const float* __restrict__ adst, float* __restrict__ ssrc,
                         float* __restrict__ sdst, int n, int heads, int ch) {
    int idx = blockIdx.x * blockDim.x + threadIdx.x;
    if (idx >= n * heads) return;
    int node = idx / heads, h = idx % heads;
    const float4* hp = reinterpret_cast<const float4*>(H + (size_t)node * heads * ch + h * ch);
    const float4* as = reinterpret_cast<const float4*>(asrc + h * ch);
    const float4* ad = reinterpret_cast<const float4*>(adst + h * ch);
    float a = 0.f, b = 0.f;
    for (int c = 0; c < ch / 4; ++c) {
        float4 v = hp[c], s = as[c], d = ad[c];
        a += v.x * s.x + v.y * s.y + v.z * s.z + v.w * s.w;
        b += v.x * d.x + v.y * d.y + v.z * d.z + v.w * d.w;
    }
    ssrc[idx] = a;
    sdst[idx] = b;
}

// ===== CSR build ============================================================
__global__ void hist_k(const int* __restrict__ ei, int E, int Etot, int* __restrict__ cnt) {
    int e = blockIdx.x * blockDim.x + threadIdx.x;
    if (e >= Etot) return;
    int d = (e < E) ? ei[E + e] : e - E;
    atomicAdd(&cnt[d], 1);
}

__global__ void scan1_k(const int* __restrict__ cnt, int* __restrict__ excl,
                        int* __restrict__ bsum, int n) {
    __shared__ int tmp[256];
    int i = blockIdx.x * 256 + threadIdx.x;
    int v = (i < n) ? cnt[i] : 0;
    tmp[threadIdx.x] = v;
    __syncthreads();
    for (int off = 1; off < 256; off <<= 1) {
        int t = (threadIdx.x >= off) ? tmp[threadIdx.x - off] : 0;
        __syncthreads();
        tmp[threadIdx.x] += t;
        __syncthreads();
    }
    if (i < n) excl[i] = tmp[threadIdx.x] - v;
    if (threadIdx.x == 255) bsum[blockIdx.x] = tmp[255];
}

__global__ void scan2_k(int* __restrict__ bsum, int nb) {
    __shared__ int tmp[512];
    int i = threadIdx.x;
    int v = (i < nb) ? bsum[i] : 0;
    tmp[i] = v;
    __syncthreads();
    for (int off = 1; off < 512; off <<= 1) {
        int t = (i >= off) ? tmp[i - off] : 0;
        __syncthreads();
        tmp[i] += t;
        __syncthreads();
    }
    if (i < nb) bsum[i] = tmp[i] - v;   // exclusive
}

__global__ void scan3_k(const int* __restrict__ excl, const int* __restrict__ bsum,
                        int* __restrict__ rowptr, int* __restrict__ cursor,
                        int n, int total) {
    int i = blockIdx.x * 256 + threadIdx.x;
    if (i < n) {
        int r = excl[i] + bsum[blockIdx.x];
        rowptr[i] = r;
        cursor[i] = r;
    }
    if (i == 0) rowptr[n] = total;
}

__global__ void scatter_k(const int* __restrict__ ei, int E, int Etot,
                          int* __restrict__ cursor, int* __restrict__ cols) {
    int e = blockIdx.x * blockDim.x + threadIdx.x;
    if (e >= Etot) return;
    int s, d;
    if (e < E) { s = ei[e]; d = ei[E + e]; } else { s = d = e - E; }
    int pos = atomicAdd(&cursor[d], 1);
    cols[pos] = s;
}

// ===== per-node softmax weights: thread per node, 2 serial passes ===========
// writes UNNORMALIZED exp weights to alpha[], reciprocal denom to rden[]
template<int HH>
__global__ void alpha_k(const int* __restrict__ rp, const int* __restrict__ cols,
                        const float* __restrict__ ssrc, const float* __restrict__ sdst,
                        float* __restrict__ alpha, float* __restrict__ rden, int n) {
    int d = blockIdx.x * 256 + threadIdx.x;
    if (d >= n) return;
    int beg = rp[d], end = rp[d + 1];

    float sd[HH];
    if constexpr (HH == 4) {
        float4 t = *reinterpret_cast<const float4*>(sdst + (size_t)d * 4);
        sd[0] = t.x; sd[1] = t.y; sd[2] = t.z; sd[3] = t.w;
    } else {
        sd[0] = sdst[d];
    }

    float m[HH];
#pragma unroll
    for (int h = 0; h < HH; ++h) m[h] = -1e30f;

    // pass 1: raw leaky logits -> alpha, track max
    for (int i = beg; i < end; ++i) {
        int s = cols[i];
        float v[HH];
        if constexpr (HH == 4) {
            float4 t = *reinterpret_cast<const float4*>(ssrc + (size_t)s * 4);
            v[0] = t.x; v[1] = t.y; v[2] = t.z; v[3] = t.w;
        } else {
            v[0] = ssrc[s];
        }
#pragma unroll
        for (int h = 0; h < HH; ++h) {
            float e = v[h] + sd[h];
            e = (e >= 0.f) ? e : NEG_SLOPE * e;
            v[h] = e;
            m[h] = fmaxf(m[h], e);
        }
        if constexpr (HH == 4)
            *reinterpret_cast<float4*>(alpha + (size_t)i * 4) = float4{v[0], v[1], v[2], v[3]};
        else
            alpha[i] = v[0];
    }

    // pass 2: exp in-place, accumulate denom
    float den[HH];
#pragma unroll
    for (int h = 0; h < HH; ++h) den[h] = 0.f;
    for (int i = beg; i < end; ++i) {
        float v[HH];
        if constexpr (HH == 4) {
            float4 t = *reinterpret_cast<const float4*>(alpha + (size_t)i * 4);
            v[0] = t.x; v[1] = t.y; v[2] = t.z; v[3] = t.w;
        } else {
            v[0] = alpha[i];
        }
#pragma unroll
        for (int h = 0; h < HH; ++h) {
            float e = __expf(v[h] - m[h]);
            v[h] = e;
            den[h] += e;
        }
        if constexpr (HH == 4)
            *reinterpret_cast<float4*>(alpha + (size_t)i * 4) = float4{v[0], v[1], v[2], v[3]};
        else
            alpha[i] = v[0];
    }
    if constexpr (HH == 4) {
        float4 r;
        r.x = 1.f / (den[0] + 1e-16f); r.y = 1.f / (den[1] + 1e-16f);
        r.z = 1.f / (den[2] + 1e-16f); r.w = 1.f / (den[3] + 1e-16f);
        *reinterpret_cast<float4*>(rden + (size_t)d * 4) = r;
    } else {
        rden[d] = 1.f / (den[0] + 1e-16f);
    }
}

// ===== layers 0/1 aggregation: 16-lane group per node, F=128 ================
// lane owns 8 channels; no cross-lane combine, no LDS, no barriers
__global__ __launch_bounds__(256) void aggr128_k(
        const int* __restrict__ rp, const int* __restrict__ cols,
        const float* __restrict__ H, const float* __restrict__ alpha,
        const float* __restrict__ rden, const float* __restrict__ bias,
        float* __restrict__ out, int n) {
    int d = (blockIdx.x * 256 + threadIdx.x) >> 4;
    if (d >= n) return;
    int l = threadIdx.x & 15;
    int head = l >> 2;                       // (l*8)/32
    int beg = rp[d], end = rp[d + 1];

    float4 a0 = {0.f, 0.f, 0.f, 0.f}, a1 = {0.f, 0.f, 0.f, 0.f};
    for (int i = beg; i < end; ++i) {
        int s = cols[i];                     // broadcast within group
        float a = alpha[(size_t)i * 4 + head];
        const float* hp = H + (size_t)s * 128 + l * 8;
        float4 v0 = *reinterpret_cast<const float4*>(hp);
        float4 v1 = *reinterpret_cast<const float4*>(hp + 4);
        a0.x += a * v0.x; a0.y += a * v0.y; a0.z += a * v0.z; a0.w += a * v0.w;
        a1.x += a * v1.x; a1.y += a * v1.y; a1.z += a * v1.z; a1.w += a * v1.w;
    }

    float r = rden[(size_t)d * 4 + head];
    float4 b0 = *reinterpret_cast<const float4*>(bias + l * 8);
    float4 b1 = *reinterpret_cast<const float4*>(bias + l * 8 + 4);
    float4 v0, v1;
    v0.x = a0.x * r + b0.x; v0.y = a0.y * r + b0.y;
    v0.z = a0.z * r + b0.z; v0.w = a0.w * r + b0.w;
    v1.x = a1.x * r + b1.x; v1.y = a1.y * r + b1.y;
    v1.z = a1.z * r + b1.z; v1.w = a1.w * r + b1.w;
    v0.x = (v0.x > 0.f) ? v0.x : expm1f(v0.x);
    v0.y = (v0.y > 0.f) ? v0.y : expm1f(v0.y);
    v0.z = (v0.z > 0.f) ? v0.z : expm1f(v0.z);
    v0.w = (v0.w > 0.f) ? v0.w : expm1f(v0.w);
    v1.x = (v1.x > 0.f) ? v1.x : expm1f(v1.x);
    v1.y = (v1.y > 0.f) ? v1.y : expm1f(v1.y);
    v1.z = (v1.z > 0.f) ? v1.z : expm1f(v1.z);
    v1.w = (v1.w > 0.f) ? v1.w : expm1f(v1.w);
    float* op = out + (size_t)d * 128 + l * 8;
    *reinterpret_cast<float4*>(op)     = v0;
    *reinterpret_cast<float4*>(op + 4) = v1;
}

// ===== layer 2 aggregation + bias + log_softmax: 16-lane group per node =====
__global__ __launch_bounds__(256) void aggr40_k(
        const int* __restrict__ rp, const int* __restrict__ cols,
        const float* __restrict__ H, const float* __restrict__ alpha,
        const float* __restrict__ rden, const float* __restrict__ b2,
        float* __restrict__ out, int n) {
    int d = (blockIdx.x * 256 + threadIdx.x) >> 4;
    if (d >= n) return;
    int l = threadIdx.x & 15;
    int beg = rp[d], end = rp[d + 1];

    float4 acc = {0.f, 0.f, 0.f, 0.f};
    for (int i = beg; i < end; ++i) {
        int s = cols[i];
        float a = alpha[i];
        if (l < 10) {
            float4 v = *reinterpret_cast<const float4*>(H + (size_t)s * 40 + l * 4);
            acc.x += a * v.x; acc.y += a * v.y; acc.z += a * v.z; acc.w += a * v.w;
        }
    }

    float r = rden[d];
    float4 v4 = {0.f, 0.f, 0.f, 0.f};
    float mm = -1e30f;
    if (l < 10) {
        float4 b = *reinterpret_cast<const float4*>(b2 + l * 4);
        v4.x = acc.x * r + b.x; v4.y = acc.y * r + b.y;
        v4.z = acc.z * r + b.z; v4.w = acc.w * r + b.w;
        mm = fmaxf(fmaxf(v4.x, v4.y), fmaxf(v4.z, v4.w));
    }
    for (int off = 8; off > 0; off >>= 1) mm = fmaxf(mm, __shfl_xor(mm, off, 16));
    float ss = 0.f;
    if (l < 10)
        ss = __expf(v4.x - mm) + __expf(v4.y - mm) + __expf(v4.z - mm) + __expf(v4.w - mm);
    for (int off = 8; off > 0; off >>= 1) ss += __shfl_xor(ss, off, 16);
    float lse = mm + logf(ss);
    if (l < 10) {
        float4 o;
        o.x = v4.x - lse; o.y = v4.y - lse; o.z = v4.z - lse; o.w = v4.w - lse;
        *reinterpret_cast<float4*>(out + (size_t)d * 40 + l * 4) = o;
    }
}

static inline dim3 g1(long t) { return dim3((unsigned)((t + 255) / 256)); }

extern "C" void kernel_launch(void* const* d_in, const int* in_sizes, int n_in,
                              void* d_out, int out_size, void* d_ws, size_t ws_size,
                              hipStream_t stream) {
    const float* x      = (const float*)d_in[0];
    const int*   ei     = (const int*)d_in[1];
    const float* W0     = (const float*)d_in[2];
    const float* a_src0 = (const float*)d_in[3];
    const float* a_dst0 = (const float*)d_in[4];
    const float* b0     = (const float*)d_in[5];
    const float* W1     = (const float*)d_in[6];
    const float* a_src1 = (const float*)d_in[7];
    const float* a_dst1 = (const float*)d_in[8];
    const float* b1     = (const float*)d_in[9];
    const float* W2     = (const float*)d_in[10];
    const float* a_src2 = (const float*)d_in[11];
    const float* a_dst2 = (const float*)d_in[12];
    const float* b2     = (const float*)d_in[13];

    const int N    = in_sizes[0] / FIN;
    const int E    = in_sizes[1] / 2;
    const int Etot = E + N;

    float* ws = (float*)d_ws;
    size_t o = 0;
    float* hA    = ws + o; o += (size_t)N * FIN;
    float* hB    = ws + o; o += (size_t)N * FIN;
    float* ssrc  = ws + o; o += (size_t)N * HEADS;
    float* sdst  = ws + o; o += (size_t)N * HEADS;
    float* alpha = ws + o; o += (size_t)Etot * HEADS;
    float* rden  = ws + o; o += (size_t)N * HEADS;
    int* cnt    = (int*)(ws + o); o += N;
    int* excl   = (int*)(ws + o); o += N;
    int* bsum   = (int*)(ws + o); o += 512;
    int* rowptr = (int*)(ws + o); o += N + 1;
    int* cursor = (int*)(ws + o); o += N;
    int* cols   = (int*)(ws + o); o += Etot;
    unsigned short* Bhi0 = (unsigned short*)(ws + o); o += 4 * 8 * 64 * 8 / 2;
    unsigned short* Blo0 = (unsigned short*)(ws + o); o += 4 * 8 * 64 * 8 / 2;
    unsigned short* Bhi1 = (unsigned short*)(ws + o); o += 4 * 8 * 64 * 8 / 2;
    unsigned short* Blo1 = (unsigned short*)(ws + o); o += 4 * 8 * 64 * 8 / 2;
    unsigned short* Bhi2 = (unsigned short*)(ws + o); o += 4 * 3 * 64 * 8 / 2;
    unsigned short* Blo2 = (unsigned short*)(ws + o); o += 4 * 3 * 64 * 8 / 2;

    const int nScanBlocks = (N + 255) / 256;
    const int gemmBlocks  = (N + 127) / 128;
    const int grpBlocks   = (N * 16 + 255) / 256;

    // ---------------- CSR by destination + weight packing (shared) ----------
    hipMemsetAsync(cnt, 0, (size_t)N * 4, stream);
    hist_k<<<g1(Etot), 256, 0, stream>>>(ei, E, Etot, cnt);
    packW_k<8><<<g1(4 * 8 * 64 * 8), 256, 0, stream>>>(W0, Bhi0, Blo0, 128);
    packW_k<8><<<g1(4 * 8 * 64 * 8), 256, 0, stream>>>(W1, Bhi1, Blo1, 128);
    packW_k<3><<<g1(4 * 3 * 64 * 8), 256, 0, stream>>>(W2, Bhi2, Blo2, NCLS);
    scan1_k<<<nScanBlocks, 256, 0, stream>>>(cnt, excl, bsum, N);
    scan2_k<<<1, 512, 0, stream>>>(bsum, nScanBlocks);
    scan3_k<<<nScanBlocks, 256, 0, stream>>>(excl, bsum, rowptr, cursor, N, Etot);
    scatter_k<<<g1(Etot), 256, 0, stream>>>(ei, E, Etot, cursor, cols);

    // ---------------- Layer 0 ----------------------------------------------
    gemm_mfma_k<8><<<gemmBlocks, 256, 0, stream>>>(x, Bhi0, Blo0, hA, N, 128);
    scores_k<<<g1((long)N * HEADS), 256, 0, stream>>>(hA, a_src0, a_dst0, ssrc, sdst, N, HEADS, HID);
    alpha_k<HEADS><<<g1(N), 256, 0, stream>>>(rowptr, cols, ssrc, sdst, alpha, rden, N);
    aggr128_k<<<grpBlocks, 256, 0, stream>>>(rowptr, cols, hA, alpha, rden, b0, hB, N);

    // ---------------- Layer 1 ----------------------------------------------
    gemm_mfma_k<8><<<gemmBlocks, 256, 0, stream>>>(hB, Bhi1, Blo1, hA, N, 128);
    scores_k<<<g1((long)N * HEADS), 256, 0, stream>>>(hA, a_src1, a_dst1, ssrc, sdst, N, HEADS, HID);
    alpha_k<HEADS><<<g1(N), 256, 0, stream>>>(rowptr, cols, ssrc, sdst, alpha, rden, N);
    aggr128_k<<<grpBlocks, 256, 0, stream>>>(rowptr, cols, hA, alpha, rden, b1, hB, N);

    // ---------------- Layer 2 (fused bias + log_softmax) --------------------
    gemm_mfma_k<3><<<gemmBlocks, 256, 0, stream>>>(hB, Bhi2, Blo2, hA, N, NCLS);
    scores_k<<<g1((long)N * 1), 256, 0, stream>>>(hA, a_src2, a_dst2, ssrc, sdst, N, 1, NCLS);
    alpha_k<1><<<g1(N), 256, 0, stream>>>(rowptr, cols, ssrc, sdst, alpha, rden, N);
    aggr40_k<<<grpBlocks, 256, 0, stream>>>(rowptr, cols, hA, alpha, rden, b2, (float*)d_out, N);
}

// Round 6
// 605.348 us; speedup vs baseline: 1.1084x; 1.1084x over previous
//
#include <hip/hip_runtime.h>
#include <hip/hip_bf16.h>

#define FIN   128
#define HEADS 4
#define HID   32
#define NCLS  40
#define NEG_SLOPE 0.2f

typedef __bf16 bf16x8 __attribute__((ext_vector_type(8)));
typedef float  f32x4  __attribute__((ext_vector_type(4)));

__device__ inline unsigned short bf16_rne(float f) {
    unsigned u = __float_as_uint(f);
    return (unsigned short)((u + 0x7fffu + ((u >> 16) & 1u)) >> 16);
}
__device__ inline float bf16_to_f(unsigned short h) {
    return __uint_as_float(((unsigned)h) << 16);
}

// ===== pack W[k,col] fp32 -> B-fragment-ordered bf16 hi/lo planes ===========
template<int NC>
__global__ void packW_k(const float* __restrict__ W, unsigned short* __restrict__ Bhi,
                        unsigned short* __restrict__ Blo, int NO) {
    int idx = blockIdx.x * 256 + threadIdx.x;
    int total = 4 * NC * 64 * 8;
    if (idx >= total) return;
    int i = idx & 7;
    int rest = idx >> 3;
    int l = rest & 63;
    int rest2 = rest >> 6;
    int c = rest2 % NC;
    int t = rest2 / NC;
    int k   = t * 32 + (l >> 4) * 8 + i;
    int col = c * 16 + (l & 15);
    float val = (col < NO) ? W[(size_t)k * NO + col] : 0.f;
    unsigned short hi = bf16_rne(val);
    unsigned short lo = bf16_rne(val - bf16_to_f(hi));
    Bhi[idx] = hi;
    Blo[idx] = lo;
}

// ===== MFMA GEMM: Y[n,NO] = X[n,128] @ W[128,NO], split-bf16 ================
template<int NC>
__global__ __launch_bounds__(256) void gemm_mfma_k(
        const float* __restrict__ X, const unsigned short* __restrict__ Bhi,
        const unsigned short* __restrict__ Blo, float* __restrict__ Y,
        int n, int NO) {
    int wave = threadIdx.x >> 6;
    int lane = threadIdx.x & 63;
    int rowbase = (blockIdx.x * 4 + wave) * 32;
    if (rowbase >= n) return;
    int r0 = lane & 15, kg = lane >> 4;

    f32x4 acc[2][NC];
#pragma unroll
    for (int rt = 0; rt < 2; ++rt)
#pragma unroll
        for (int c = 0; c < NC; ++c) acc[rt][c] = f32x4{0.f, 0.f, 0.f, 0.f};

    for (int t = 0; t < 4; ++t) {
        union U { unsigned short u[8]; bf16x8 v; };
        U ah[2], al[2];
#pragma unroll
        for (int rt = 0; rt < 2; ++rt) {
            int row = min(rowbase + rt * 16 + r0, n - 1);
            const float* xp = X + (size_t)row * 128 + t * 32 + kg * 8;
            float4 xa = *reinterpret_cast<const float4*>(xp);
            float4 xb = *reinterpret_cast<const float4*>(xp + 4);
            float f[8] = {xa.x, xa.y, xa.z, xa.w, xb.x, xb.y, xb.z, xb.w};
#pragma unroll
            for (int i = 0; i < 8; ++i) {
                unsigned short h = bf16_rne(f[i]);
                ah[rt].u[i] = h;
                al[rt].u[i] = bf16_rne(f[i] - bf16_to_f(h));
            }
        }
#pragma unroll
        for (int c = 0; c < NC; ++c) {
            size_t boff = (((size_t)t * NC + c) * 64 + lane) * 8;
            bf16x8 bh = *reinterpret_cast<const bf16x8*>(Bhi + boff);
            bf16x8 bl = *reinterpret_cast<const bf16x8*>(Blo + boff);
#pragma unroll
            for (int rt = 0; rt < 2; ++rt) {
                acc[rt][c] = __builtin_amdgcn_mfma_f32_16x16x32_bf16(ah[rt].v, bh, acc[rt][c], 0, 0, 0);
                acc[rt][c] = __builtin_amdgcn_mfma_f32_16x16x32_bf16(al[rt].v, bh, acc[rt][c], 0, 0, 0);
                acc[rt][c] = __builtin_amdgcn_mfma_f32_16x16x32_bf16(ah[rt].v, bl, acc[rt][c], 0, 0, 0);
            }
        }
    }

#pragma unroll
    for (int rt = 0; rt < 2; ++rt)
#pragma unroll
        for (int c = 0; c < NC; ++c)
#pragma unroll
            for (int r = 0; r < 4; ++r) {
                int row = rowbase + rt * 16 + kg * 4 + r;
                int col = c * 16 + r0;
                if (row < n && col < NO)
                    Y[(size_t)row * NO + col] = acc[rt][c][r];
            }
}

// ===== attention logits per node (float4) ===================================
__global__ void scores_k(const float* __restrict__ H, const float* __restrict__ asrc,
                         const float* __restrict__ adst, float* __restrict__ ssrc,
                         float* __restrict__ sdst, int n, int heads, int ch) {
    int idx = blockIdx.x * blockDim.x + threadIdx.x;
    if (idx >= n * heads) return;
    int node = idx / heads, h = idx % heads;
    const float4* hp = reinterpret_cast<const float4*>(H + (size_t)node * heads * ch + h * ch);
    const float4* as = reinterpret_cast<const float4*>(asrc + h * ch);
    const float4* ad = reinterpret_cast<const float4*>(adst + h * ch);
    float a = 0.f, b = 0.f;
    for (int c = 0; c < ch / 4; ++c) {
        float4 v = hp[c], s = as[c], d = ad[c];
        a += v.x * s.x + v.y * s.y + v.z * s.z + v.w * s.w;
        b += v.x * d.x + v.y * d.y + v.z * d.z + v.w * d.w;
    }
    ssrc[idx] = a;
    sdst[idx] = b;
}

// ===== CSR build ============================================================
__global__ void hist_k(const int* __restrict__ ei, int E, int Etot, int* __restrict__ cnt) {
    int e = blockIdx.x * blockDim.x + threadIdx.x;
    if (e >= Etot) return;
    int d = (e < E) ? ei[E + e] : e - E;
    atomicAdd(&cnt[d], 1);
}

__global__ void scan1_k(const int* __restrict__ cnt, int* __restrict__ excl,
                        int* __restrict__ bsum, int n) {
    __shared__ int tmp[256];
    int i = blockIdx.x * 256 + threadIdx.x;
    int v = (i < n) ? cnt[i] : 0;
    tmp[threadIdx.x] = v;
    __syncthreads();
    for (int off = 1; off < 256; off <<= 1) {
        int t = (threadIdx.x >= off) ? tmp[threadIdx.x - off] : 0;
        __syncthreads();
        tmp[threadIdx.x] += t;
        __syncthreads();
    }
    if (i < n) excl[i] = tmp[threadIdx.x] - v;
    if (threadIdx.x == 255) bsum[blockIdx.x] = tmp[255];
}

__global__ void scan2_k(int* __restrict__ bsum, int nb) {
    __shared__ int tmp[512];
    int i = threadIdx.x;
    int v = (i < nb) ? bsum[i] : 0;
    tmp[i] = v;
    __syncthreads();
    for (int off = 1; off < 512; off <<= 1) {
        int t = (i >= off) ? tmp[i - off] : 0;
        __syncthreads();
        tmp[i] += t;
        __syncthreads();
    }
    if (i < nb) bsum[i] = tmp[i] - v;   // exclusive
}

__global__ void scan3_k(const int* __restrict__ excl, const int* __restrict__ bsum,
                        int* __restrict__ rowptr, int* __restrict__ cursor,
                        int n, int total) {
    int i = blockIdx.x * 256 + threadIdx.x;
    if (i < n) {
        int r = excl[i] + bsum[blockIdx.x];
        rowptr[i] = r;
        cursor[i] = r;
    }
    if (i == 0) rowptr[n] = total;
}

__global__ void scatter_k(const int* __restrict__ ei, int E, int Etot,
                          int* __restrict__ cursor, int* __restrict__ cols) {
    int e = blockIdx.x * blockDim.x + threadIdx.x;
    if (e >= Etot) return;
    int s, d;
    if (e < E) { s = ei[e]; d = ei[E + e]; } else { s = d = e - E; }
    int pos = atomicAdd(&cursor[d], 1);
    cols[pos] = s;
}

// ===== layers 0/1: fully fused softmax + aggregation, 16-lane group/node ====
// lane l: head = l>>2, owns channels l*8..l*8+7. Phase 1: edges split across
// the 4 lanes of the head subgroup (online max+denom, 2 shfl merges).
// Phase 2: every lane walks all edges, recomputes its head's alpha on the fly.
__global__ __launch_bounds__(256) void gat128_k(
        const int* __restrict__ rp, const int* __restrict__ cols,
        const float* __restrict__ H, const float* __restrict__ ssrc,
        const float* __restrict__ sdst, const float* __restrict__ bias,
        float* __restrict__ out, int n) {
    int d = (blockIdx.x * 256 + threadIdx.x) >> 4;
    if (d >= n) return;
    int l = threadIdx.x & 15;
    int head = l >> 2;
    int sub  = l & 3;
    int beg = rp[d], end = rp[d + 1];

    float sdh = sdst[(size_t)d * 4 + head];

    // ---- phase 1: online max+denom over this head's edges, 4-way split ----
    float m = -1e30f, den = 0.f;
    for (int i = beg + sub; i < end; i += 4) {
        int s = cols[i];
        float v = ssrc[(size_t)s * 4 + head] + sdh;
        v = (v >= 0.f) ? v : NEG_SLOPE * v;
        float nm = fmaxf(m, v);
        den = den * __expf(m - nm) + __expf(v - nm);
        m = nm;
    }
#pragma unroll
    for (int off = 1; off <= 2; off <<= 1) {
        float om = __shfl_xor(m, off, 64);
        float od = __shfl_xor(den, off, 64);
        float nm = fmaxf(m, om);
        den = den * __expf(m - nm) + od * __expf(om - nm);
        m = nm;
    }
    float r = 1.f / (den + 1e-16f);

    // ---- phase 2: aggregate with on-the-fly unnormalized weights ----
    float4 a0 = {0.f, 0.f, 0.f, 0.f}, a1 = {0.f, 0.f, 0.f, 0.f};
    for (int i = beg; i < end; ++i) {
        int s = cols[i];
        float v = ssrc[(size_t)s * 4 + head] + sdh;
        v = (v >= 0.f) ? v : NEG_SLOPE * v;
        float a = __expf(v - m);
        const float* hp = H + (size_t)s * 128 + l * 8;
        float4 v0 = *reinterpret_cast<const float4*>(hp);
        float4 v1 = *reinterpret_cast<const float4*>(hp + 4);
        a0.x += a * v0.x; a0.y += a * v0.y; a0.z += a * v0.z; a0.w += a * v0.w;
        a1.x += a * v1.x; a1.y += a * v1.y; a1.z += a * v1.z; a1.w += a * v1.w;
    }

    // ---- epilogue: normalize + bias + ELU ----
    float4 b0 = *reinterpret_cast<const float4*>(bias + l * 8);
    float4 b1 = *reinterpret_cast<const float4*>(bias + l * 8 + 4);
    float4 v0, v1;
    v0.x = a0.x * r + b0.x; v0.y = a0.y * r + b0.y;
    v0.z = a0.z * r + b0.z; v0.w = a0.w * r + b0.w;
    v1.x = a1.x * r + b1.x; v1.y = a1.y * r + b1.y;
    v1.z = a1.z * r + b1.z; v1.w = a1.w * r + b1.w;
    v0.x = (v0.x > 0.f) ? v0.x : expm1f(v0.x);
    v0.y = (v0.y > 0.f) ? v0.y : expm1f(v0.y);
    v0.z = (v0.z > 0.f) ? v0.z : expm1f(v0.z);
    v0.w = (v0.w > 0.f) ? v0.w : expm1f(v0.w);
    v1.x = (v1.x > 0.f) ? v1.x : expm1f(v1.x);
    v1.y = (v1.y > 0.f) ? v1.y : expm1f(v1.y);
    v1.z = (v1.z > 0.f) ? v1.z : expm1f(v1.z);
    v1.w = (v1.w > 0.f) ? v1.w : expm1f(v1.w);
    float* op = out + (size_t)d * 128 + l * 8;
    *reinterpret_cast<float4*>(op)     = v0;
    *reinterpret_cast<float4*>(op + 4) = v1;
}

// ===== layer 2: fused softmax + aggregation + bias + log_softmax ============
__global__ __launch_bounds__(256) void gat40_k(
        const int* __restrict__ rp, const int* __restrict__ cols,
        const float* __restrict__ H, const float* __restrict__ ssrc,
        const float* __restrict__ sdst, const float* __restrict__ b2,
        float* __restrict__ out, int n) {
    int d = (blockIdx.x * 256 + threadIdx.x) >> 4;
    if (d >= n) return;
    int l = threadIdx.x & 15;
    int beg = rp[d], end = rp[d + 1];
    float sd = sdst[d];

    // ---- phase 1: online max+denom, 16-way split ----
    float m = -1e30f, den = 0.f;
    for (int i = beg + l; i < end; i += 16) {
        int s = cols[i];
        float v = ssrc[s] + sd;
        v = (v >= 0.f) ? v : NEG_SLOPE * v;
        float nm = fmaxf(m, v);
        den = den * __expf(m - nm) + __expf(v - nm);
        m = nm;
    }
#pragma unroll
    for (int off = 1; off <= 8; off <<= 1) {
        float om = __shfl_xor(m, off, 64);
        float od = __shfl_xor(den, off, 64);
        float nm = fmaxf(m, om);
        den = den * __expf(m - nm) + od * __expf(om - nm);
        m = nm;
    }
    float r = 1.f / (den + 1e-16f);

    // ---- phase 2: lanes 0-9 aggregate 4 channels each ----
    float4 acc = {0.f, 0.f, 0.f, 0.f};
    for (int i = beg; i < end; ++i) {
        int s = cols[i];
        float v = ssrc[s] + sd;
        v = (v >= 0.f) ? v : NEG_SLOPE * v;
        float a = __expf(v - m);
        if (l < 10) {
            float4 h4 = *reinterpret_cast<const float4*>(H + (size_t)s * 40 + l * 4);
            acc.x += a * h4.x; acc.y += a * h4.y; acc.z += a * h4.z; acc.w += a * h4.w;
        }
    }

    // ---- epilogue: normalize + bias + log_softmax over 40 logits ----
    float4 v4 = {0.f, 0.f, 0.f, 0.f};
    float mm = -1e30f;
    if (l < 10) {
        float4 b = *reinterpret_cast<const float4*>(b2 + l * 4);
        v4.x = acc.x * r + b.x; v4.y = acc.y * r + b.y;
        v4.z = acc.z * r + b.z; v4.w = acc.w * r + b.w;
        mm = fmaxf(fmaxf(v4.x, v4.y), fmaxf(v4.z, v4.w));
    }
    for (int off = 8; off > 0; off >>= 1) mm = fmaxf(mm, __shfl_xor(mm, off, 16));
    float ss = 0.f;
    if (l < 10)
        ss = __expf(v4.x - mm) + __expf(v4.y - mm) + __expf(v4.z - mm) + __expf(v4.w - mm);
    for (int off = 8; off > 0; off >>= 1) ss += __shfl_xor(ss, off, 16);
    float lse = mm + logf(ss);
    if (l < 10) {
        float4 o;
        o.x = v4.x - lse; o.y = v4.y - lse; o.z = v4.z - lse; o.w = v4.w - lse;
        *reinterpret_cast<float4*>(out + (size_t)d * 40 + l * 4) = o;
    }
}

static inline dim3 g1(long t) { return dim3((unsigned)((t + 255) / 256)); }

extern "C" void kernel_launch(void* const* d_in, const int* in_sizes, int n_in,
                              void* d_out, int out_size, void* d_ws, size_t ws_size,
                              hipStream_t stream) {
    const float* x      = (const float*)d_in[0];
    const int*   ei     = (const int*)d_in[1];
    const float* W0     = (const float*)d_in[2];
    const float* a_src0 = (const float*)d_in[3];
    const float* a_dst0 = (const float*)d_in[4];
    const float* b0     = (const float*)d_in[5];
    const float* W1     = (const float*)d_in[6];
    const float* a_src1 = (const float*)d_in[7];
    const float* a_dst1 = (const float*)d_in[8];
    const float* b1     = (const float*)d_in[9];
    const float* W2     = (const float*)d_in[10];
    const float* a_src2 = (const float*)d_in[11];
    const float* a_dst2 = (const float*)d_in[12];
    const float* b2     = (const float*)d_in[13];

    const int N    = in_sizes[0] / FIN;
    const int E    = in_sizes[1] / 2;
    const int Etot = E + N;

    float* ws = (float*)d_ws;
    size_t o = 0;
    float* hA    = ws + o; o += (size_t)N * FIN;
    float* hB    = ws + o; o += (size_t)N * FIN;
    float* ssrc  = ws + o; o += (size_t)N * HEADS;
    float* sdst  = ws + o; o += (size_t)N * HEADS;
    int* cnt    = (int*)(ws + o); o += N;
    int* excl   = (int*)(ws + o); o += N;
    int* bsum   = (int*)(ws + o); o += 512;
    int* rowptr = (int*)(ws + o); o += N + 1;
    int* cursor = (int*)(ws + o); o += N;
    int* cols   = (int*)(ws + o); o += Etot;
    unsigned short* Bhi0 = (unsigned short*)(ws + o); o += 4 * 8 * 64 * 8 / 2;
    unsigned short* Blo0 = (unsigned short*)(ws + o); o += 4 * 8 * 64 * 8 / 2;
    unsigned short* Bhi1 = (unsigned short*)(ws + o); o += 4 * 8 * 64 * 8 / 2;
    unsigned short* Blo1 = (unsigned short*)(ws + o); o += 4 * 8 * 64 * 8 / 2;
    unsigned short* Bhi2 = (unsigned short*)(ws + o); o += 4 * 3 * 64 * 8 / 2;
    unsigned short* Blo2 = (unsigned short*)(ws + o); o += 4 * 3 * 64 * 8 / 2;

    const int nScanBlocks = (N + 255) / 256;
    const int gemmBlocks  = (N + 127) / 128;
    const int grpBlocks   = (N * 16 + 255) / 256;

    // ---------------- CSR by destination + weight packing (shared) ----------
    hipMemsetAsync(cnt, 0, (size_t)N * 4, stream);
    hist_k<<<g1(Etot), 256, 0, stream>>>(ei, E, Etot, cnt);
    packW_k<8><<<g1(4 * 8 * 64 * 8), 256, 0, stream>>>(W0, Bhi0, Blo0, 128);
    packW_k<8><<<g1(4 * 8 * 64 * 8), 256, 0, stream>>>(W1, Bhi1, Blo1, 128);
    packW_k<3><<<g1(4 * 3 * 64 * 8), 256, 0, stream>>>(W2, Bhi2, Blo2, NCLS);
    scan1_k<<<nScanBlocks, 256, 0, stream>>>(cnt, excl, bsum, N);
    scan2_k<<<1, 512, 0, stream>>>(bsum, nScanBlocks);
    scan3_k<<<nScanBlocks, 256, 0, stream>>>(excl, bsum, rowptr, cursor, N, Etot);
    scatter_k<<<g1(Etot), 256, 0, stream>>>(ei, E, Etot, cursor, cols);

    // ---------------- Layer 0 ----------------------------------------------
    gemm_mfma_k<8><<<gemmBlocks, 256, 0, stream>>>(x, Bhi0, Blo0, hA, N, 128);
    scores_k<<<g1((long)N * HEADS), 256, 0, stream>>>(hA, a_src0, a_dst0, ssrc, sdst, N, HEADS, HID);
    gat128_k<<<grpBlocks, 256, 0, stream>>>(rowptr, cols, hA, ssrc, sdst, b0, hB, N);

    // ---------------- Layer 1 ----------------------------------------------
    gemm_mfma_k<8><<<gemmBlocks, 256, 0, stream>>>(hB, Bhi1, Blo1, hA, N, 128);
    scores_k<<<g1((long)N * HEADS), 256, 0, stream>>>(hA, a_src1, a_dst1, ssrc, sdst, N, HEADS, HID);
    gat128_k<<<grpBlocks, 256, 0, stream>>>(rowptr, cols, hA, ssrc, sdst, b1, hB, N);

    // ---------------- Layer 2 (fused bias + log_softmax) --------------------
    gemm_mfma_k<3><<<gemmBlocks, 256, 0, stream>>>(hB, Bhi2, Blo2, hA, N, NCLS);
    scores_k<<<g1((long)N * 1), 256, 0, stream>>>(hA, a_src2, a_dst2, ssrc, sdst, N, 1, NCLS);
    gat40_k<<<grpBlocks, 256, 0, stream>>>(rowptr, cols, hA, ssrc, sdst, b2, (float*)d_out, N);
}

// Round 7
// 515.979 us; speedup vs baseline: 1.3004x; 1.1732x over previous
//
#include <hip/hip_runtime.h>
#include <hip/hip_bf16.h>

#define FIN   128
#define HEADS 4
#define HID   32
#define NCLS  40
#define NEG_SLOPE 0.2f

typedef __bf16 bf16x8 __attribute__((ext_vector_type(8)));
typedef float  f32x4  __attribute__((ext_vector_type(4)));

__device__ inline unsigned short bf16_rne(float f) {
    unsigned u = __float_as_uint(f);
    return (unsigned short)((u + 0x7fffu + ((u >> 16) & 1u)) >> 16);
}
__device__ inline float bf16_to_f(unsigned short h) {
    return __uint_as_float(((unsigned)h) << 16);
}

// ===== pack W[k,col] fp32 -> B-fragment-ordered bf16 hi/lo planes ===========
template<int NC>
__global__ void packW_k(const float* __restrict__ W, unsigned short* __restrict__ Bhi,
                        unsigned short* __restrict__ Blo, int NO) {
    int idx = blockIdx.x * 256 + threadIdx.x;
    int total = 4 * NC * 64 * 8;
    if (idx >= total) return;
    int i = idx & 7;
    int rest = idx >> 3;
    int l = rest & 63;
    int rest2 = rest >> 6;
    int c = rest2 % NC;
    int t = rest2 / NC;
    int k   = t * 32 + (l >> 4) * 8 + i;
    int col = c * 16 + (l & 15);
    float val = (col < NO) ? W[(size_t)k * NO + col] : 0.f;
    unsigned short hi = bf16_rne(val);
    unsigned short lo = bf16_rne(val - bf16_to_f(hi));
    Bhi[idx] = hi;
    Blo[idx] = lo;
}

// ===== MFMA GEMM: Y[n,NO] = X[n,128] @ W[128,NO], split-bf16 ================
template<int NC>
__global__ __launch_bounds__(256) void gemm_mfma_k(
        const float* __restrict__ X, const unsigned short* __restrict__ Bhi,
        const unsigned short* __restrict__ Blo, float* __restrict__ Y,
        int n, int NO) {
    int wave = threadIdx.x >> 6;
    int lane = threadIdx.x & 63;
    int rowbase = (blockIdx.x * 4 + wave) * 32;
    if (rowbase >= n) return;
    int r0 = lane & 15, kg = lane >> 4;

    f32x4 acc[2][NC];
#pragma unroll
    for (int rt = 0; rt < 2; ++rt)
#pragma unroll
        for (int c = 0; c < NC; ++c) acc[rt][c] = f32x4{0.f, 0.f, 0.f, 0.f};

    for (int t = 0; t < 4; ++t) {
        union U { unsigned short u[8]; bf16x8 v; };
        U ah[2], al[2];
#pragma unroll
        for (int rt = 0; rt < 2; ++rt) {
            int row = min(rowbase + rt * 16 + r0, n - 1);
            const float* xp = X + (size_t)row * 128 + t * 32 + kg * 8;
            float4 xa = *reinterpret_cast<const float4*>(xp);
            float4 xb = *reinterpret_cast<const float4*>(xp + 4);
            float f[8] = {xa.x, xa.y, xa.z, xa.w, xb.x, xb.y, xb.z, xb.w};
#pragma unroll
            for (int i = 0; i < 8; ++i) {
                unsigned short h = bf16_rne(f[i]);
                ah[rt].u[i] = h;
                al[rt].u[i] = bf16_rne(f[i] - bf16_to_f(h));
            }
        }
#pragma unroll
        for (int c = 0; c < NC; ++c) {
            size_t boff = (((size_t)t * NC + c) * 64 + lane) * 8;
            bf16x8 bh = *reinterpret_cast<const bf16x8*>(Bhi + boff);
            bf16x8 bl = *reinterpret_cast<const bf16x8*>(Blo + boff);
#pragma unroll
            for (int rt = 0; rt < 2; ++rt) {
                acc[rt][c] = __builtin_amdgcn_mfma_f32_16x16x32_bf16(ah[rt].v, bh, acc[rt][c], 0, 0, 0);
                acc[rt][c] = __builtin_amdgcn_mfma_f32_16x16x32_bf16(al[rt].v, bh, acc[rt][c], 0, 0, 0);
                acc[rt][c] = __builtin_amdgcn_mfma_f32_16x16x32_bf16(ah[rt].v, bl, acc[rt][c], 0, 0, 0);
            }
        }
    }

#pragma unroll
    for (int rt = 0; rt < 2; ++rt)
#pragma unroll
        for (int c = 0; c < NC; ++c)
#pragma unroll
            for (int r = 0; r < 4; ++r) {
                int row = rowbase + rt * 16 + kg * 4 + r;
                int col = c * 16 + r0;
                if (row < n && col < NO)
                    Y[(size_t)row * NO + col] = acc[rt][c][r];
            }
}

// ===== attention logits per node + bf16 copy of H ===========================
// thread = (node, head); reads its 32/40-ch chunk, writes dots + bf16 chunk
template<int HH, int CH>
__global__ void scores_bf_k(const float* __restrict__ H, const float* __restrict__ asrc,
                            const float* __restrict__ adst, float* __restrict__ ssrc,
                            float* __restrict__ sdst, unsigned short* __restrict__ Hbf,
                            int n) {
    int idx = blockIdx.x * blockDim.x + threadIdx.x;
    if (idx >= n * HH) return;
    int node = idx / HH, h = idx % HH;
    const float4* hp = reinterpret_cast<const float4*>(H + (size_t)node * (HH * CH) + h * CH);
    const float4* as = reinterpret_cast<const float4*>(asrc + h * CH);
    const float4* ad = reinterpret_cast<const float4*>(adst + h * CH);
    unsigned short* op = Hbf + (size_t)node * (HH * CH) + h * CH;
    float a = 0.f, b = 0.f;
#pragma unroll
    for (int c = 0; c < CH / 4; ++c) {
        float4 v = hp[c], s = as[c], d = ad[c];
        a += v.x * s.x + v.y * s.y + v.z * s.z + v.w * s.w;
        b += v.x * d.x + v.y * d.y + v.z * d.z + v.w * d.w;
        ushort4 u;
        u.x = bf16_rne(v.x); u.y = bf16_rne(v.y);
        u.z = bf16_rne(v.z); u.w = bf16_rne(v.w);
        *reinterpret_cast<ushort4*>(op + c * 4) = u;
    }
    ssrc[idx] = a;
    sdst[idx] = b;
}

// ===== CSR build ============================================================
__global__ void hist_k(const int* __restrict__ ei, int E, int Etot, int* __restrict__ cnt) {
    int e = blockIdx.x * blockDim.x + threadIdx.x;
    if (e >= Etot) return;
    int d = (e < E) ? ei[E + e] : e - E;
    atomicAdd(&cnt[d], 1);
}

__global__ void scan1_k(const int* __restrict__ cnt, int* __restrict__ excl,
                        int* __restrict__ bsum, int n) {
    __shared__ int tmp[256];
    int i = blockIdx.x * 256 + threadIdx.x;
    int v = (i < n) ? cnt[i] : 0;
    tmp[threadIdx.x] = v;
    __syncthreads();
    for (int off = 1; off < 256; off <<= 1) {
        int t = (threadIdx.x >= off) ? tmp[threadIdx.x - off] : 0;
        __syncthreads();
        tmp[threadIdx.x] += t;
        __syncthreads();
    }
    if (i < n) excl[i] = tmp[threadIdx.x] - v;
    if (threadIdx.x == 255) bsum[blockIdx.x] = tmp[255];
}

__global__ void scan2_k(int* __restrict__ bsum, int nb) {
    __shared__ int tmp[512];
    int i = threadIdx.x;
    int v = (i < nb) ? bsum[i] : 0;
    tmp[i] = v;
    __syncthreads();
    for (int off = 1; off < 512; off <<= 1) {
        int t = (i >= off) ? tmp[i - off] : 0;
        __syncthreads();
        tmp[i] += t;
        __syncthreads();
    }
    if (i < nb) bsum[i] = tmp[i] - v;   // exclusive
}

__global__ void scan3_k(const int* __restrict__ excl, const int* __restrict__ bsum,
                        int* __restrict__ rowptr, int* __restrict__ cursor,
                        int n, int total) {
    int i = blockIdx.x * 256 + threadIdx.x;
    if (i < n) {
        int r = excl[i] + bsum[blockIdx.x];
        rowptr[i] = r;
        cursor[i] = r;
    }
    if (i == 0) rowptr[n] = total;
}

__global__ void scatter_k(const int* __restrict__ ei, int E, int Etot,
                          int* __restrict__ cursor, int* __restrict__ cols) {
    int e = blockIdx.x * blockDim.x + threadIdx.x;
    if (e >= Etot) return;
    int s, d;
    if (e < E) { s = ei[e]; d = ei[E + e]; } else { s = d = e - E; }
    int pos = atomicAdd(&cursor[d], 1);
    cols[pos] = s;
}

// ===== layers 0/1: fused softmax + bf16 aggregation, 16-lane group/node =====
__global__ __launch_bounds__(256) void gat128_k(
        const int* __restrict__ rp, const int* __restrict__ cols,
        const unsigned short* __restrict__ Hbf, const float* __restrict__ ssrc,
        const float* __restrict__ sdst, const float* __restrict__ bias,
        float* __restrict__ out, int n) {
    int d = (blockIdx.x * 256 + threadIdx.x) >> 4;
    if (d >= n) return;
    int l = threadIdx.x & 15;
    int head = l >> 2;
    int sub  = l & 3;
    int beg = rp[d], end = rp[d + 1];

    float sdh = sdst[(size_t)d * 4 + head];

    // ---- phase 1: online max+denom over this head's edges, 4-way split ----
    float m = -1e30f, den = 0.f;
    for (int i = beg + sub; i < end; i += 4) {
        int s = cols[i];
        float v = ssrc[(size_t)s * 4 + head] + sdh;
        v = (v >= 0.f) ? v : NEG_SLOPE * v;
        float nm = fmaxf(m, v);
        den = den * __expf(m - nm) + __expf(v - nm);
        m = nm;
    }
#pragma unroll
    for (int off = 1; off <= 2; off <<= 1) {
        float om = __shfl_xor(m, off, 64);
        float od = __shfl_xor(den, off, 64);
        float nm = fmaxf(m, om);
        den = den * __expf(m - nm) + od * __expf(om - nm);
        m = nm;
    }
    float r = 1.f / (den + 1e-16f);

    // ---- phase 2: gather bf16 rows (16B/lane), fp32 accumulate ----
    float4 a0 = {0.f, 0.f, 0.f, 0.f}, a1 = {0.f, 0.f, 0.f, 0.f};
    for (int i = beg; i < end; ++i) {
        int s = cols[i];
        float v = ssrc[(size_t)s * 4 + head] + sdh;
        v = (v >= 0.f) ? v : NEG_SLOPE * v;
        float a = __expf(v - m);
        const unsigned short* hp = Hbf + (size_t)s * 128 + l * 8;
        uint4 q = *reinterpret_cast<const uint4*>(hp);
        float f0 = __uint_as_float(q.x << 16);
        float f1 = __uint_as_float(q.x & 0xffff0000u);
        float f2 = __uint_as_float(q.y << 16);
        float f3 = __uint_as_float(q.y & 0xffff0000u);
        float f4 = __uint_as_float(q.z << 16);
        float f5 = __uint_as_float(q.z & 0xffff0000u);
        float f6 = __uint_as_float(q.w << 16);
        float f7 = __uint_as_float(q.w & 0xffff0000u);
        a0.x += a * f0; a0.y += a * f1; a0.z += a * f2; a0.w += a * f3;
        a1.x += a * f4; a1.y += a * f5; a1.z += a * f6; a1.w += a * f7;
    }

    // ---- epilogue: normalize + bias + ELU ----
    float4 b0 = *reinterpret_cast<const float4*>(bias + l * 8);
    float4 b1 = *reinterpret_cast<const float4*>(bias + l * 8 + 4);
    float4 v0, v1;
    v0.x = a0.x * r + b0.x; v0.y = a0.y * r + b0.y;
    v0.z = a0.z * r + b0.z; v0.w = a0.w * r + b0.w;
    v1.x = a1.x * r + b1.x; v1.y = a1.y * r + b1.y;
    v1.z = a1.z * r + b1.z; v1.w = a1.w * r + b1.w;
    v0.x = (v0.x > 0.f) ? v0.x : expm1f(v0.x);
    v0.y = (v0.y > 0.f) ? v0.y : expm1f(v0.y);
    v0.z = (v0.z > 0.f) ? v0.z : expm1f(v0.z);
    v0.w = (v0.w > 0.f) ? v0.w : expm1f(v0.w);
    v1.x = (v1.x > 0.f) ? v1.x : expm1f(v1.x);
    v1.y = (v1.y > 0.f) ? v1.y : expm1f(v1.y);
    v1.z = (v1.z > 0.f) ? v1.z : expm1f(v1.z);
    v1.w = (v1.w > 0.f) ? v1.w : expm1f(v1.w);
    float* op = out + (size_t)d * 128 + l * 8;
    *reinterpret_cast<float4*>(op)     = v0;
    *reinterpret_cast<float4*>(op + 4) = v1;
}

// ===== layer 2: fused softmax + bf16 aggregation + bias + log_softmax =======
__global__ __launch_bounds__(256) void gat40_k(
        const int* __restrict__ rp, const int* __restrict__ cols,
        const unsigned short* __restrict__ Hbf, const float* __restrict__ ssrc,
        const float* __restrict__ sdst, const float* __restrict__ b2,
        float* __restrict__ out, int n) {
    int d = (blockIdx.x * 256 + threadIdx.x) >> 4;
    if (d >= n) return;
    int l = threadIdx.x & 15;
    int beg = rp[d], end = rp[d + 1];
    float sd = sdst[d];

    // ---- phase 1: online max+denom, 16-way split ----
    float m = -1e30f, den = 0.f;
    for (int i = beg + l; i < end; i += 16) {
        int s = cols[i];
        float v = ssrc[s] + sd;
        v = (v >= 0.f) ? v : NEG_SLOPE * v;
        float nm = fmaxf(m, v);
        den = den * __expf(m - nm) + __expf(v - nm);
        m = nm;
    }
#pragma unroll
    for (int off = 1; off <= 8; off <<= 1) {
        float om = __shfl_xor(m, off, 64);
        float od = __shfl_xor(den, off, 64);
        float nm = fmaxf(m, om);
        den = den * __expf(m - nm) + od * __expf(om - nm);
        m = nm;
    }
    float r = 1.f / (den + 1e-16f);

    // ---- phase 2: lanes 0-9 aggregate 4 bf16 channels each ----
    float4 acc = {0.f, 0.f, 0.f, 0.f};
    for (int i = beg; i < end; ++i) {
        int s = cols[i];
        float v = ssrc[s] + sd;
        v = (v >= 0.f) ? v : NEG_SLOPE * v;
        float a = __expf(v - m);
        if (l < 10) {
            uint2 q = *reinterpret_cast<const uint2*>(Hbf + (size_t)s * 40 + l * 4);
            float f0 = __uint_as_float(q.x << 16);
            float f1 = __uint_as_float(q.x & 0xffff0000u);
            float f2 = __uint_as_float(q.y << 16);
            float f3 = __uint_as_float(q.y & 0xffff0000u);
            acc.x += a * f0; acc.y += a * f1; acc.z += a * f2; acc.w += a * f3;
        }
    }

    // ---- epilogue: normalize + bias + log_softmax over 40 logits ----
    float4 v4 = {0.f, 0.f, 0.f, 0.f};
    float mm = -1e30f;
    if (l < 10) {
        float4 b = *reinterpret_cast<const float4*>(b2 + l * 4);
        v4.x = acc.x * r + b.x; v4.y = acc.y * r + b.y;
        v4.z = acc.z * r + b.z; v4.w = acc.w * r + b.w;
        mm = fmaxf(fmaxf(v4.x, v4.y), fmaxf(v4.z, v4.w));
    }
    for (int off = 8; off > 0; off >>= 1) mm = fmaxf(mm, __shfl_xor(mm, off, 16));
    float ss = 0.f;
    if (l < 10)
        ss = __expf(v4.x - mm) + __expf(v4.y - mm) + __expf(v4.z - mm) + __expf(v4.w - mm);
    for (int off = 8; off > 0; off >>= 1) ss += __shfl_xor(ss, off, 16);
    float lse = mm + logf(ss);
    if (l < 10) {
        float4 o;
        o.x = v4.x - lse; o.y = v4.y - lse; o.z = v4.z - lse; o.w = v4.w - lse;
        *reinterpret_cast<float4*>(out + (size_t)d * 40 + l * 4) = o;
    }
}

static inline dim3 g1(long t) { return dim3((unsigned)((t + 255) / 256)); }

extern "C" void kernel_launch(void* const* d_in, const int* in_sizes, int n_in,
                              void* d_out, int out_size, void* d_ws, size_t ws_size,
                              hipStream_t stream) {
    const float* x      = (const float*)d_in[0];
    const int*   ei     = (const int*)d_in[1];
    const float* W0     = (const float*)d_in[2];
    const float* a_src0 = (const float*)d_in[3];
    const float* a_dst0 = (const float*)d_in[4];
    const float* b0     = (const float*)d_in[5];
    const float* W1     = (const float*)d_in[6];
    const float* a_src1 = (const float*)d_in[7];
    const float* a_dst1 = (const float*)d_in[8];
    const float* b1     = (const float*)d_in[9];
    const float* W2     = (const float*)d_in[10];
    const float* a_src2 = (const float*)d_in[11];
    const float* a_dst2 = (const float*)d_in[12];
    const float* b2     = (const float*)d_in[13];

    const int N    = in_sizes[0] / FIN;
    const int E    = in_sizes[1] / 2;
    const int Etot = E + N;

    float* ws = (float*)d_ws;
    size_t o = 0;
    float* hA    = ws + o; o += (size_t)N * FIN;
    float* hB    = ws + o; o += (size_t)N * FIN;
    float* ssrc  = ws + o; o += (size_t)N * HEADS;
    float* sdst  = ws + o; o += (size_t)N * HEADS;
    unsigned short* Hbf = (unsigned short*)(ws + o); o += (size_t)N * FIN / 2;
    int* cnt    = (int*)(ws + o); o += N;
    int* excl   = (int*)(ws + o); o += N;
    int* bsum   = (int*)(ws + o); o += 512;
    int* rowptr = (int*)(ws + o); o += N + 1;
    int* cursor = (int*)(ws + o); o += N;
    int* cols   = (int*)(ws + o); o += Etot;
    unsigned short* Bhi0 = (unsigned short*)(ws + o); o += 4 * 8 * 64 * 8 / 2;
    unsigned short* Blo0 = (unsigned short*)(ws + o); o += 4 * 8 * 64 * 8 / 2;
    unsigned short* Bhi1 = (unsigned short*)(ws + o); o += 4 * 8 * 64 * 8 / 2;
    unsigned short* Blo1 = (unsigned short*)(ws + o); o += 4 * 8 * 64 * 8 / 2;
    unsigned short* Bhi2 = (unsigned short*)(ws + o); o += 4 * 3 * 64 * 8 / 2;
    unsigned short* Blo2 = (unsigned short*)(ws + o); o += 4 * 3 * 64 * 8 / 2;

    const int nScanBlocks = (N + 255) / 256;
    const int gemmBlocks  = (N + 127) / 128;
    const int grpBlocks   = (N * 16 + 255) / 256;

    // ---------------- CSR by destination + weight packing (shared) ----------
    hipMemsetAsync(cnt, 0, (size_t)N * 4, stream);
    hist_k<<<g1(Etot), 256, 0, stream>>>(ei, E, Etot, cnt);
    packW_k<8><<<g1(4 * 8 * 64 * 8), 256, 0, stream>>>(W0, Bhi0, Blo0, 128);
    packW_k<8><<<g1(4 * 8 * 64 * 8), 256, 0, stream>>>(W1, Bhi1, Blo1, 128);
    packW_k<3><<<g1(4 * 3 * 64 * 8), 256, 0, stream>>>(W2, Bhi2, Blo2, NCLS);
    scan1_k<<<nScanBlocks, 256, 0, stream>>>(cnt, excl, bsum, N);
    scan2_k<<<1, 512, 0, stream>>>(bsum, nScanBlocks);
    scan3_k<<<nScanBlocks, 256, 0, stream>>>(excl, bsum, rowptr, cursor, N, Etot);
    scatter_k<<<g1(Etot), 256, 0, stream>>>(ei, E, Etot, cursor, cols);

    // ---------------- Layer 0 ----------------------------------------------
    gemm_mfma_k<8><<<gemmBlocks, 256, 0, stream>>>(x, Bhi0, Blo0, hA, N, 128);
    scores_bf_k<HEADS, HID><<<g1((long)N * HEADS), 256, 0, stream>>>(hA, a_src0, a_dst0, ssrc, sdst, Hbf, N);
    gat128_k<<<grpBlocks, 256, 0, stream>>>(rowptr, cols, Hbf, ssrc, sdst, b0, hB, N);

    // ---------------- Layer 1 ----------------------------------------------
    gemm_mfma_k<8><<<gemmBlocks, 256, 0, stream>>>(hB, Bhi1, Blo1, hA, N, 128);
    scores_bf_k<HEADS, HID><<<g1((long)N * HEADS), 256, 0, stream>>>(hA, a_src1, a_dst1, ssrc, sdst, Hbf, N);
    gat128_k<<<grpBlocks, 256, 0, stream>>>(rowptr, cols, Hbf, ssrc, sdst, b1, hB, N);

    // ---------------- Layer 2 (fused bias + log_softmax) --------------------
    gemm_mfma_k<3><<<gemmBlocks, 256, 0, stream>>>(hB, Bhi2, Blo2, hA, N, NCLS);
    scores_bf_k<1, NCLS><<<g1((long)N * 1), 256, 0, stream>>>(hA, a_src2, a_dst2, ssrc, sdst, Hbf, N);
    gat40_k<<<grpBlocks, 256, 0, stream>>>(rowptr, cols, Hbf, ssrc, sdst, b2, (float*)d_out, N);
}

// Round 8
// 439.146 us; speedup vs baseline: 1.5279x; 1.1750x over previous
//
#include <hip/hip_runtime.h>
#include <hip/hip_bf16.h>

#define FIN   128
#define HEADS 4
#define HID   32
#define NCLS  40
#define NEG_SLOPE 0.2f

#define BKT_SH 10          // 1024 dsts per bucket
#define BKT    1024
#define NB_MAX 128
#define TILE_E 4096        // edges per block in bucket passes

typedef __bf16 bf16x8 __attribute__((ext_vector_type(8)));
typedef float  f32x4  __attribute__((ext_vector_type(4)));

__device__ inline unsigned short bf16_rne(float f) {
    unsigned u = __float_as_uint(f);
    return (unsigned short)((u + 0x7fffu + ((u >> 16) & 1u)) >> 16);
}
__device__ inline float bf16_to_f(unsigned short h) {
    return __uint_as_float(((unsigned)h) << 16);
}

// ===== pack W[k,col] fp32 -> B-fragment-ordered bf16 hi/lo planes ===========
template<int NC>
__global__ void packW_k(const float* __restrict__ W, unsigned short* __restrict__ Bhi,
                        unsigned short* __restrict__ Blo, int NO) {
    int idx = blockIdx.x * 256 + threadIdx.x;
    int total = 4 * NC * 64 * 8;
    if (idx >= total) return;
    int i = idx & 7;
    int rest = idx >> 3;
    int l = rest & 63;
    int rest2 = rest >> 6;
    int c = rest2 % NC;
    int t = rest2 / NC;
    int k   = t * 32 + (l >> 4) * 8 + i;
    int col = c * 16 + (l & 15);
    float val = (col < NO) ? W[(size_t)k * NO + col] : 0.f;
    unsigned short hi = bf16_rne(val);
    unsigned short lo = bf16_rne(val - bf16_to_f(hi));
    Bhi[idx] = hi;
    Blo[idx] = lo;
}

// ===== MFMA GEMM: Y[n,NO] = X[n,128] @ W[128,NO], split-bf16 ================
template<int NC>
__global__ __launch_bounds__(256) void gemm_mfma_k(
        const float* __restrict__ X, const unsigned short* __restrict__ Bhi,
        const unsigned short* __restrict__ Blo, float* __restrict__ Y,
        int n, int NO) {
    int wave = threadIdx.x >> 6;
    int lane = threadIdx.x & 63;
    int rowbase = (blockIdx.x * 4 + wave) * 32;
    if (rowbase >= n) return;
    int r0 = lane & 15, kg = lane >> 4;

    f32x4 acc[2][NC];
#pragma unroll
    for (int rt = 0; rt < 2; ++rt)
#pragma unroll
        for (int c = 0; c < NC; ++c) acc[rt][c] = f32x4{0.f, 0.f, 0.f, 0.f};

    for (int t = 0; t < 4; ++t) {
        union U { unsigned short u[8]; bf16x8 v; };
        U ah[2], al[2];
#pragma unroll
        for (int rt = 0; rt < 2; ++rt) {
            int row = min(rowbase + rt * 16 + r0, n - 1);
            const float* xp = X + (size_t)row * 128 + t * 32 + kg * 8;
            float4 xa = *reinterpret_cast<const float4*>(xp);
            float4 xb = *reinterpret_cast<const float4*>(xp + 4);
            float f[8] = {xa.x, xa.y, xa.z, xa.w, xb.x, xb.y, xb.z, xb.w};
#pragma unroll
            for (int i = 0; i < 8; ++i) {
                unsigned short h = bf16_rne(f[i]);
                ah[rt].u[i] = h;
                al[rt].u[i] = bf16_rne(f[i] - bf16_to_f(h));
            }
        }
#pragma unroll
        for (int c = 0; c < NC; ++c) {
            size_t boff = (((size_t)t * NC + c) * 64 + lane) * 8;
            bf16x8 bh = *reinterpret_cast<const bf16x8*>(Bhi + boff);
            bf16x8 bl = *reinterpret_cast<const bf16x8*>(Blo + boff);
#pragma unroll
            for (int rt = 0; rt < 2; ++rt) {
                acc[rt][c] = __builtin_amdgcn_mfma_f32_16x16x32_bf16(ah[rt].v, bh, acc[rt][c], 0, 0, 0);
                acc[rt][c] = __builtin_amdgcn_mfma_f32_16x16x32_bf16(al[rt].v, bh, acc[rt][c], 0, 0, 0);
                acc[rt][c] = __builtin_amdgcn_mfma_f32_16x16x32_bf16(ah[rt].v, bl, acc[rt][c], 0, 0, 0);
            }
        }
    }

#pragma unroll
    for (int rt = 0; rt < 2; ++rt)
#pragma unroll
        for (int c = 0; c < NC; ++c)
#pragma unroll
            for (int r = 0; r < 4; ++r) {
                int row = rowbase + rt * 16 + kg * 4 + r;
                int col = c * 16 + r0;
                if (row < n && col < NO)
                    Y[(size_t)row * NO + col] = acc[rt][c][r];
            }
}

// ===== attention logits per node + bf16 copy of H ===========================
template<int HH, int CH>
__global__ void scores_bf_k(const float* __restrict__ H, const float* __restrict__ asrc,
                            const float* __restrict__ adst, float* __restrict__ ssrc,
                            float* __restrict__ sdst, unsigned short* __restrict__ Hbf,
                            int n) {
    int idx = blockIdx.x * blockDim.x + threadIdx.x;
    if (idx >= n * HH) return;
    int node = idx / HH, h = idx % HH;
    const float4* hp = reinterpret_cast<const float4*>(H + (size_t)node * (HH * CH) + h * CH);
    const float4* as = reinterpret_cast<const float4*>(asrc + h * CH);
    const float4* ad = reinterpret_cast<const float4*>(adst + h * CH);
    unsigned short* op = Hbf + (size_t)node * (HH * CH) + h * CH;
    float a = 0.f, b = 0.f;
#pragma unroll
    for (int c = 0; c < CH / 4; ++c) {
        float4 v = hp[c], s = as[c], d = ad[c];
        a += v.x * s.x + v.y * s.y + v.z * s.z + v.w * s.w;
        b += v.x * d.x + v.y * d.y + v.z * d.z + v.w * d.w;
        ushort4 u;
        u.x = bf16_rne(v.x); u.y = bf16_rne(v.y);
        u.z = bf16_rne(v.z); u.w = bf16_rne(v.w);
        *reinterpret_cast<ushort4*>(op + c * 4) = u;
    }
    ssrc[idx] = a;
    sdst[idx] = b;
}

// ===== CSR build, two-level bucket partition ================================
// L1: coarse histogram into NB buckets (dst >> BKT_SH)
__global__ __launch_bounds__(256) void histA_k(const int* __restrict__ ei, int E, int Etot,
                                               int nb, int* __restrict__ cnt1) {
    __shared__ int h[NB_MAX];
    for (int i = threadIdx.x; i < nb; i += 256) h[i] = 0;
    __syncthreads();
    int base = blockIdx.x * TILE_E;
    int lim = min(base + TILE_E, Etot);
    for (int e = base + threadIdx.x; e < lim; e += 256) {
        int d = (e < E) ? ei[E + e] : e - E;
        atomicAdd(&h[d >> BKT_SH], 1);
    }
    __syncthreads();
    for (int i = threadIdx.x; i < nb; i += 256)
        if (h[i]) atomicAdd(&cnt1[i], h[i]);
}

// scan bucket counts -> bases + cursors (single 128-thread block)
__global__ void scanB_k(const int* __restrict__ cnt1, int* __restrict__ bbase,
                        int* __restrict__ gcur1, int nb) {
    __shared__ int tmp[128];
    int l = threadIdx.x;
    int v = (l < nb) ? cnt1[l] : 0;
    tmp[l] = v;
    __syncthreads();
    for (int off = 1; off < 128; off <<= 1) {
        int t = (l >= off) ? tmp[l - off] : 0;
        __syncthreads();
        tmp[l] += t;
        __syncthreads();
    }
    if (l < nb) { int ex = tmp[l] - v; bbase[l] = ex; gcur1[l] = ex; }
    if (l == 0) bbase[nb] = tmp[127];
}

// partition (src,dst) pairs into bucket regions; per-block contiguous runs
__global__ __launch_bounds__(256) void placeA_k(const int* __restrict__ ei, int E, int Etot,
                                                int nb, int* __restrict__ gcur1,
                                                int2* __restrict__ pairs) {
    __shared__ int h[NB_MAX];
    __shared__ int cur[NB_MAX];
    for (int i = threadIdx.x; i < nb; i += 256) h[i] = 0;
    __syncthreads();
    int base = blockIdx.x * TILE_E;
    int lim = min(base + TILE_E, Etot);
    for (int e = base + threadIdx.x; e < lim; e += 256) {
        int d = (e < E) ? ei[E + e] : e - E;
        atomicAdd(&h[d >> BKT_SH], 1);
    }
    __syncthreads();
    for (int i = threadIdx.x; i < nb; i += 256)
        cur[i] = h[i] ? atomicAdd(&gcur1[i], h[i]) : 0;
    __syncthreads();
    for (int e = base + threadIdx.x; e < lim; e += 256) {
        int s, d;
        if (e < E) { s = ei[e]; d = ei[E + e]; } else { s = d = e - E; }
        int p = atomicAdd(&cur[d >> BKT_SH], 1);
        pairs[p] = make_int2(s, d);
    }
}

// per-bucket CSR finalize: LDS hist over 1024 dsts + LDS scan; writes stay in
// a ~53KB L2-resident window -> full-line writebacks
__global__ __launch_bounds__(256) void buildcsr_k(const int2* __restrict__ pairs,
                                                  const int* __restrict__ bbase,
                                                  int* __restrict__ rowptr,
                                                  int* __restrict__ cols,
                                                  int n, int etot) {
    __shared__ int cnt[BKT];
    __shared__ int part[256];
    int b = blockIdx.x;
    int d0 = b << BKT_SH;
    int nd = min(BKT, n - d0);
    int rbeg = bbase[b], rend = bbase[b + 1];
    for (int i = threadIdx.x; i < nd; i += 256) cnt[i] = 0;
    __syncthreads();
    for (int i = rbeg + threadIdx.x; i < rend; i += 256)
        atomicAdd(&cnt[pairs[i].y - d0], 1);
    __syncthreads();

    int t = threadIdx.x;
    int i4 = t * 4;
    int myv[4];
    int s0 = 0;
#pragma unroll
    for (int j = 0; j < 4; ++j) { myv[j] = (i4 + j < nd) ? cnt[i4 + j] : 0; s0 += myv[j]; }
    part[t] = s0;
    __syncthreads();
    for (int off = 1; off < 256; off <<= 1) {
        int tv = (t >= off) ? part[t - off] : 0;
        __syncthreads();
        part[t] += tv;
        __syncthreads();
    }
    int run = rbeg + part[t] - s0;
#pragma unroll
    for (int j = 0; j < 4; ++j) {
        if (i4 + j < nd) {
            rowptr[d0 + i4 + j] = run;
            cnt[i4 + j] = run;          // becomes absolute cursor
            run += myv[j];
        }
    }
    if (b == 0 && t == 0) rowptr[n] = etot;
    __syncthreads();
    for (int i = rbeg + threadIdx.x; i < rend; i += 256) {
        int2 p = pairs[i];
        int pos = atomicAdd(&cnt[p.y - d0], 1);
        cols[pos] = p.x;
    }
}

// ===== layers 0/1: fused softmax + bf16 aggregation, 16-lane group/node =====
__global__ __launch_bounds__(256) void gat128_k(
        const int* __restrict__ rp, const int* __restrict__ cols,
        const unsigned short* __restrict__ Hbf, const float* __restrict__ ssrc,
        const float* __restrict__ sdst, const float* __restrict__ bias,
        float* __restrict__ out, int n) {
    int d = (blockIdx.x * 256 + threadIdx.x) >> 4;
    if (d >= n) return;
    int l = threadIdx.x & 15;
    int head = l >> 2;
    int sub  = l & 3;
    int beg = rp[d], end = rp[d + 1];

    float sdh = sdst[(size_t)d * 4 + head];

    float m = -1e30f, den = 0.f;
    for (int i = beg + sub; i < end; i += 4) {
        int s = cols[i];
        float v = ssrc[(size_t)s * 4 + head] + sdh;
        v = (v >= 0.f) ? v : NEG_SLOPE * v;
        float nm = fmaxf(m, v);
        den = den * __expf(m - nm) + __expf(v - nm);
        m = nm;
    }
#pragma unroll
    for (int off = 1; off <= 2; off <<= 1) {
        float om = __shfl_xor(m, off, 64);
        float od = __shfl_xor(den, off, 64);
        float nm = fmaxf(m, om);
        den = den * __expf(m - nm) + od * __expf(om - nm);
        m = nm;
    }
    float r = 1.f / (den + 1e-16f);

    float4 a0 = {0.f, 0.f, 0.f, 0.f}, a1 = {0.f, 0.f, 0.f, 0.f};
    for (int i = beg; i < end; ++i) {
        int s = cols[i];
        float v = ssrc[(size_t)s * 4 + head] + sdh;
        v = (v >= 0.f) ? v : NEG_SLOPE * v;
        float a = __expf(v - m);
        const unsigned short* hp = Hbf + (size_t)s * 128 + l * 8;
        uint4 q = *reinterpret_cast<const uint4*>(hp);
        float f0 = __uint_as_float(q.x << 16);
        float f1 = __uint_as_float(q.x & 0xffff0000u);
        float f2 = __uint_as_float(q.y << 16);
        float f3 = __uint_as_float(q.y & 0xffff0000u);
        float f4 = __uint_as_float(q.z << 16);
        float f5 = __uint_as_float(q.z & 0xffff0000u);
        float f6 = __uint_as_float(q.w << 16);
        float f7 = __uint_as_float(q.w & 0xffff0000u);
        a0.x += a * f0; a0.y += a * f1; a0.z += a * f2; a0.w += a * f3;
        a1.x += a * f4; a1.y += a * f5; a1.z += a * f6; a1.w += a * f7;
    }

    float4 b0 = *reinterpret_cast<const float4*>(bias + l * 8);
    float4 b1 = *reinterpret_cast<const float4*>(bias + l * 8 + 4);
    float4 v0, v1;
    v0.x = a0.x * r + b0.x; v0.y = a0.y * r + b0.y;
    v0.z = a0.z * r + b0.z; v0.w = a0.w * r + b0.w;
    v1.x = a1.x * r + b1.x; v1.y = a1.y * r + b1.y;
    v1.z = a1.z * r + b1.z; v1.w = a1.w * r + b1.w;
    v0.x = (v0.x > 0.f) ? v0.x : expm1f(v0.x);
    v0.y = (v0.y > 0.f) ? v0.y : expm1f(v0.y);
    v0.z = (v0.z > 0.f) ? v0.z : expm1f(v0.z);
    v0.w = (v0.w > 0.f) ? v0.w : expm1f(v0.w);
    v1.x = (v1.x > 0.f) ? v1.x : expm1f(v1.x);
    v1.y = (v1.y > 0.f) ? v1.y : expm1f(v1.y);
    v1.z = (v1.z > 0.f) ? v1.z : expm1f(v1.z);
    v1.w = (v1.w > 0.f) ? v1.w : expm1f(v1.w);
    float* op = out + (size_t)d * 128 + l * 8;
    *reinterpret_cast<float4*>(op)     = v0;
    *reinterpret_cast<float4*>(op + 4) = v1;
}

// ===== layer 2: fused softmax + bf16 aggregation + bias + log_softmax =======
__global__ __launch_bounds__(256) void gat40_k(
        const int* __restrict__ rp, const int* __restrict__ cols,
        const unsigned short* __restrict__ Hbf, const float* __restrict__ ssrc,
        const float* __restrict__ sdst, const float* __restrict__ b2,
        float* __restrict__ out, int n) {
    int d = (blockIdx.x * 256 + threadIdx.x) >> 4;
    if (d >= n) return;
    int l = threadIdx.x & 15;
    int beg = rp[d], end = rp[d + 1];
    float sd = sdst[d];

    float m = -1e30f, den = 0.f;
    for (int i = beg + l; i < end; i += 16) {
        int s = cols[i];
        float v = ssrc[s] + sd;
        v = (v >= 0.f) ? v : NEG_SLOPE * v;
        float nm = fmaxf(m, v);
        den = den * __expf(m - nm) + __expf(v - nm);
        m = nm;
    }
#pragma unroll
    for (int off = 1; off <= 8; off <<= 1) {
        float om = __shfl_xor(m, off, 64);
        float od = __shfl_xor(den, off, 64);
        float nm = fmaxf(m, om);
        den = den * __expf(m - nm) + od * __expf(om - nm);
        m = nm;
    }
    float r = 1.f / (den + 1e-16f);

    float4 acc = {0.f, 0.f, 0.f, 0.f};
    for (int i = beg; i < end; ++i) {
        int s = cols[i];
        float v = ssrc[s] + sd;
        v = (v >= 0.f) ? v : NEG_SLOPE * v;
        float a = __expf(v - m);
        if (l < 10) {
            uint2 q = *reinterpret_cast<const uint2*>(Hbf + (size_t)s * 40 + l * 4);
            float f0 = __uint_as_float(q.x << 16);
            float f1 = __uint_as_float(q.x & 0xffff0000u);
            float f2 = __uint_as_float(q.y << 16);
            float f3 = __uint_as_float(q.y & 0xffff0000u);
            acc.x += a * f0; acc.y += a * f1; acc.z += a * f2; acc.w += a * f3;
        }
    }

    float4 v4 = {0.f, 0.f, 0.f, 0.f};
    float mm = -1e30f;
    if (l < 10) {
        float4 b = *reinterpret_cast<const float4*>(b2 + l * 4);
        v4.x = acc.x * r + b.x; v4.y = acc.y * r + b.y;
        v4.z = acc.z * r + b.z; v4.w = acc.w * r + b.w;
        mm = fmaxf(fmaxf(v4.x, v4.y), fmaxf(v4.z, v4.w));
    }
    for (int off = 8; off > 0; off >>= 1) mm = fmaxf(mm, __shfl_xor(mm, off, 16));
    float ss = 0.f;
    if (l < 10)
        ss = __expf(v4.x - mm) + __expf(v4.y - mm) + __expf(v4.z - mm) + __expf(v4.w - mm);
    for (int off = 8; off > 0; off >>= 1) ss += __shfl_xor(ss, off, 16);
    float lse = mm + logf(ss);
    if (l < 10) {
        float4 o;
        o.x = v4.x - lse; o.y = v4.y - lse; o.z = v4.z - lse; o.w = v4.w - lse;
        *reinterpret_cast<float4*>(out + (size_t)d * 40 + l * 4) = o;
    }
}

static inline dim3 g1(long t) { return dim3((unsigned)((t + 255) / 256)); }

extern "C" void kernel_launch(void* const* d_in, const int* in_sizes, int n_in,
                              void* d_out, int out_size, void* d_ws, size_t ws_size,
                              hipStream_t stream) {
    const float* x      = (const float*)d_in[0];
    const int*   ei     = (const int*)d_in[1];
    const float* W0     = (const float*)d_in[2];
    const float* a_src0 = (const float*)d_in[3];
    const float* a_dst0 = (const float*)d_in[4];
    const float* b0     = (const float*)d_in[5];
    const float* W1     = (const float*)d_in[6];
    const float* a_src1 = (const float*)d_in[7];
    const float* a_dst1 = (const float*)d_in[8];
    const float* b1     = (const float*)d_in[9];
    const float* W2     = (const float*)d_in[10];
    const float* a_src2 = (const float*)d_in[11];
    const float* a_dst2 = (const float*)d_in[12];
    const float* b2     = (const float*)d_in[13];

    const int N    = in_sizes[0] / FIN;
    const int E    = in_sizes[1] / 2;
    const int Etot = E + N;
    const int NB   = (N + BKT - 1) / BKT;          // coarse buckets (<=128)

    float* ws = (float*)d_ws;
    size_t o = 0;
    float* hA    = ws + o; o += (size_t)N * FIN;
    float* hB    = ws + o; o += (size_t)N * FIN;
    float* ssrc  = ws + o; o += (size_t)N * HEADS;
    float* sdst  = ws + o; o += (size_t)N * HEADS;
    unsigned short* Hbf = (unsigned short*)(ws + o); o += (size_t)N * FIN / 2;
    int* cnt1   = (int*)(ws + o); o += NB_MAX;
    int* bbase  = (int*)(ws + o); o += NB_MAX + 2;
    int* gcur1  = (int*)(ws + o); o += NB_MAX;
    int* rowptr = (int*)(ws + o); o += N + 1;
    int* cols   = (int*)(ws + o); o += Etot;
    int2* pairs = (int2*)(ws + o); o += (size_t)Etot * 2;
    unsigned short* Bhi0 = (unsigned short*)(ws + o); o += 4 * 8 * 64 * 8 / 2;
    unsigned short* Blo0 = (unsigned short*)(ws + o); o += 4 * 8 * 64 * 8 / 2;
    unsigned short* Bhi1 = (unsigned short*)(ws + o); o += 4 * 8 * 64 * 8 / 2;
    unsigned short* Blo1 = (unsigned short*)(ws + o); o += 4 * 8 * 64 * 8 / 2;
    unsigned short* Bhi2 = (unsigned short*)(ws + o); o += 4 * 3 * 64 * 8 / 2;
    unsigned short* Blo2 = (unsigned short*)(ws + o); o += 4 * 3 * 64 * 8 / 2;

    const int gemmBlocks = (N + 127) / 128;
    const int grpBlocks  = (N * 16 + 255) / 256;
    const int eTiles     = (Etot + TILE_E - 1) / TILE_E;

    // ---------------- CSR build (two-level bucket partition) ----------------
    hipMemsetAsync(cnt1, 0, NB_MAX * 4, stream);
    histA_k<<<eTiles, 256, 0, stream>>>(ei, E, Etot, NB, cnt1);
    packW_k<8><<<g1(4 * 8 * 64 * 8), 256, 0, stream>>>(W0, Bhi0, Blo0, 128);
    packW_k<8><<<g1(4 * 8 * 64 * 8), 256, 0, stream>>>(W1, Bhi1, Blo1, 128);
    packW_k<3><<<g1(4 * 3 * 64 * 8), 256, 0, stream>>>(W2, Bhi2, Blo2, NCLS);
    scanB_k<<<1, 128, 0, stream>>>(cnt1, bbase, gcur1, NB);
    placeA_k<<<eTiles, 256, 0, stream>>>(ei, E, Etot, NB, gcur1, pairs);
    buildcsr_k<<<NB, 256, 0, stream>>>(pairs, bbase, rowptr, cols, N, Etot);

    // ---------------- Layer 0 ----------------------------------------------
    gemm_mfma_k<8><<<gemmBlocks, 256, 0, stream>>>(x, Bhi0, Blo0, hA, N, 128);
    scores_bf_k<HEADS, HID><<<g1((long)N * HEADS), 256, 0, stream>>>(hA, a_src0, a_dst0, ssrc, sdst, Hbf, N);
    gat128_k<<<grpBlocks, 256, 0, stream>>>(rowptr, cols, Hbf, ssrc, sdst, b0, hB, N);

    // ---------------- Layer 1 ----------------------------------------------
    gemm_mfma_k<8><<<gemmBlocks, 256, 0, stream>>>(hB, Bhi1, Blo1, hA, N, 128);
    scores_bf_k<HEADS, HID><<<g1((long)N * HEADS), 256, 0, stream>>>(hA, a_src1, a_dst1, ssrc, sdst, Hbf, N);
    gat128_k<<<grpBlocks, 256, 0, stream>>>(rowptr, cols, Hbf, ssrc, sdst, b1, hB, N);

    // ---------------- Layer 2 (fused bias + log_softmax) --------------------
    gemm_mfma_k<3><<<gemmBlocks, 256, 0, stream>>>(hB, Bhi2, Blo2, hA, N, NCLS);
    scores_bf_k<1, NCLS><<<g1((long)N * 1), 256, 0, stream>>>(hA, a_src2, a_dst2, ssrc, sdst, Hbf, N);
    gat40_k<<<grpBlocks, 256, 0, stream>>>(rowptr, cols, Hbf, ssrc, sdst, b2, (float*)d_out, N);
}

// Round 10
// 375.791 us; speedup vs baseline: 1.7855x; 1.1686x over previous
//
#include <hip/hip_runtime.h>
#include <hip/hip_bf16.h>

#define FIN   128
#define HEADS 4
#define HID   32
#define NCLS  40
#define NEG_SLOPE 0.2f

#define BKT_SH 10          // 1024 dsts per bucket
#define BKT    1024
#define NB_MAX 128
#define TILE_E 4096        // edges per block in bucket passes

typedef __bf16 bf16x8 __attribute__((ext_vector_type(8)));
typedef float  f32x4  __attribute__((ext_vector_type(4)));

__device__ inline unsigned short bf16_rne(float f) {
    unsigned u = __float_as_uint(f);
    return (unsigned short)((u + 0x7fffu + ((u >> 16) & 1u)) >> 16);
}
__device__ inline float bf16_to_f(unsigned short h) {
    return __uint_as_float(((unsigned)h) << 16);
}

// ===== pack W[k,col] fp32 -> B-fragment-ordered bf16 hi/lo planes ===========
template<int NC>
__global__ void packW_k(const float* __restrict__ W, unsigned short* __restrict__ Bhi,
                        unsigned short* __restrict__ Blo, int NO) {
    int idx = blockIdx.x * 256 + threadIdx.x;
    int total = 4 * NC * 64 * 8;
    if (idx >= total) return;
    int i = idx & 7;
    int rest = idx >> 3;
    int l = rest & 63;
    int rest2 = rest >> 6;
    int c = rest2 % NC;
    int t = rest2 / NC;
    int k   = t * 32 + (l >> 4) * 8 + i;
    int col = c * 16 + (l & 15);
    float val = (col < NO) ? W[(size_t)k * NO + col] : 0.f;
    unsigned short hi = bf16_rne(val);
    unsigned short lo = bf16_rne(val - bf16_to_f(hi));
    Bhi[idx] = hi;
    Blo[idx] = lo;
}

// ===== pack W-contracted score vectors into one B fragment ==================
// Wa[k][j] = sum_c W[k][j*CH+c] * asrc[j][c]          (j <  HH)
//          = sum_c W[k][(j-HH)*CH+c] * adst[j-HH][c]  (HH <= j < 2HH)
// so that X @ Wa == scores (s_src | s_dst) directly.
template<int HH, int CH>
__global__ void packS_k(const float* __restrict__ W, const float* __restrict__ asrc,
                        const float* __restrict__ adst, unsigned short* __restrict__ Shi,
                        unsigned short* __restrict__ Slo, int NO) {
    int idx = blockIdx.x * 256 + threadIdx.x;
    int total = 4 * 64 * 8;
    if (idx >= total) return;
    int i = idx & 7;
    int l = (idx >> 3) & 63;
    int t = idx >> 9;
    int k = t * 32 + (l >> 4) * 8 + i;
    int j = l & 15;
    float val = 0.f;
    if (j < HH) {
        const float* wr = W + (size_t)k * NO + j * CH;
        const float* av = asrc + j * CH;
        for (int c = 0; c < CH; ++c) val += wr[c] * av[c];
    } else if (j < 2 * HH) {
        int h = j - HH;
        const float* wr = W + (size_t)k * NO + h * CH;
        const float* av = adst + h * CH;
        for (int c = 0; c < CH; ++c) val += wr[c] * av[c];
    }
    unsigned short hi = bf16_rne(val);
    unsigned short lo = bf16_rne(val - bf16_to_f(hi));
    Shi[idx] = hi;
    Slo[idx] = lo;
}

// ===== fused GEMM + scores + bf16 emit ======================================
template<int NC, int HH>
__global__ __launch_bounds__(256) void gemm_fused_k(
        const float* __restrict__ X, const unsigned short* __restrict__ Bhi,
        const unsigned short* __restrict__ Blo, const unsigned short* __restrict__ Shi,
        const unsigned short* __restrict__ Slo, unsigned short* __restrict__ Hbf,
        float* __restrict__ ssrc, float* __restrict__ sdst, int n, int NO) {
    int wave = threadIdx.x >> 6;
    int lane = threadIdx.x & 63;
    int rowbase = (blockIdx.x * 4 + wave) * 32;
    if (rowbase >= n) return;
    int r0 = lane & 15, kg = lane >> 4;

    f32x4 acc[2][NC];
    f32x4 accS[2];
#pragma unroll
    for (int rt = 0; rt < 2; ++rt) {
        accS[rt] = f32x4{0.f, 0.f, 0.f, 0.f};
#pragma unroll
        for (int c = 0; c < NC; ++c) acc[rt][c] = f32x4{0.f, 0.f, 0.f, 0.f};
    }

    for (int t = 0; t < 4; ++t) {
        union U { unsigned short u[8]; bf16x8 v; };
        U ah[2], al[2];
#pragma unroll
        for (int rt = 0; rt < 2; ++rt) {
            int row = min(rowbase + rt * 16 + r0, n - 1);
            const float* xp = X + (size_t)row * 128 + t * 32 + kg * 8;
            float4 xa = *reinterpret_cast<const float4*>(xp);
            float4 xb = *reinterpret_cast<const float4*>(xp + 4);
            float f[8] = {xa.x, xa.y, xa.z, xa.w, xb.x, xb.y, xb.z, xb.w};
#pragma unroll
            for (int i = 0; i < 8; ++i) {
                unsigned short h = bf16_rne(f[i]);
                ah[rt].u[i] = h;
                al[rt].u[i] = bf16_rne(f[i] - bf16_to_f(h));
            }
        }
#pragma unroll
        for (int c = 0; c < NC; ++c) {
            size_t boff = (((size_t)t * NC + c) * 64 + lane) * 8;
            bf16x8 bh = *reinterpret_cast<const bf16x8*>(Bhi + boff);
            bf16x8 bl = *reinterpret_cast<const bf16x8*>(Blo + boff);
#pragma unroll
            for (int rt = 0; rt < 2; ++rt) {
                acc[rt][c] = __builtin_amdgcn_mfma_f32_16x16x32_bf16(ah[rt].v, bh, acc[rt][c], 0, 0, 0);
                acc[rt][c] = __builtin_amdgcn_mfma_f32_16x16x32_bf16(al[rt].v, bh, acc[rt][c], 0, 0, 0);
                acc[rt][c] = __builtin_amdgcn_mfma_f32_16x16x32_bf16(ah[rt].v, bl, acc[rt][c], 0, 0, 0);
            }
        }
        // score MFMAs (2*HH score cols packed into one fragment)
        {
            size_t soff = ((size_t)t * 64 + lane) * 8;
            bf16x8 sh = *reinterpret_cast<const bf16x8*>(Shi + soff);
            bf16x8 sl = *reinterpret_cast<const bf16x8*>(Slo + soff);
#pragma unroll
            for (int rt = 0; rt < 2; ++rt) {
                accS[rt] = __builtin_amdgcn_mfma_f32_16x16x32_bf16(ah[rt].v, sh, accS[rt], 0, 0, 0);
                accS[rt] = __builtin_amdgcn_mfma_f32_16x16x32_bf16(al[rt].v, sh, accS[rt], 0, 0, 0);
                accS[rt] = __builtin_amdgcn_mfma_f32_16x16x32_bf16(ah[rt].v, sl, accS[rt], 0, 0, 0);
            }
        }
    }

    // ---- epilogue: bf16 rows + score stores ----
#pragma unroll
    for (int rt = 0; rt < 2; ++rt)
#pragma unroll
        for (int r = 0; r < 4; ++r) {
            int row = rowbase + rt * 16 + kg * 4 + r;
            if (row >= n) continue;
            if (HH == 4) {
                if (r0 < 4)      ssrc[(size_t)row * 4 + r0]       = accS[rt][r];
                else if (r0 < 8) sdst[(size_t)row * 4 + (r0 - 4)] = accS[rt][r];
            } else {
                if (r0 == 0)      ssrc[row] = accS[rt][r];
                else if (r0 == 1) sdst[row] = accS[rt][r];
            }
#pragma unroll
            for (int c = 0; c < NC; ++c) {
                int col = c * 16 + r0;
                if (col < NO)
                    Hbf[(size_t)row * NO + col] = bf16_rne(acc[rt][c][r]);
            }
        }
}

// ===== CSR build, two-level bucket partition ================================
__global__ __launch_bounds__(256) void histA_k(const int* __restrict__ ei, int E, int Etot,
                                               int nb, int* __restrict__ cnt1) {
    __shared__ int h[NB_MAX];
    for (int i = threadIdx.x; i < nb; i += 256) h[i] = 0;
    __syncthreads();
    int base = blockIdx.x * TILE_E;
    int lim = min(base + TILE_E, Etot);
    for (int e = base + threadIdx.x; e < lim; e += 256) {
        int d = (e < E) ? ei[E + e] : e - E;
        atomicAdd(&h[d >> BKT_SH], 1);
    }
    __syncthreads();
    for (int i = threadIdx.x; i < nb; i += 256)
        if (h[i]) atomicAdd(&cnt1[i], h[i]);
}

__global__ void scanB_k(const int* __restrict__ cnt1, int* __restrict__ bbase,
                        int* __restrict__ gcur1, int nb) {
    __shared__ int tmp[128];
    int l = threadIdx.x;
    int v = (l < nb) ? cnt1[l] : 0;
    tmp[l] = v;
    __syncthreads();
    for (int off = 1; off < 128; off <<= 1) {
        int t = (l >= off) ? tmp[l - off] : 0;
        __syncthreads();
        tmp[l] += t;
        __syncthreads();
    }
    if (l < nb) { int ex = tmp[l] - v; bbase[l] = ex; gcur1[l] = ex; }
    if (l == 0) bbase[nb] = tmp[127];
}

__global__ __launch_bounds__(256) void placeA_k(const int* __restrict__ ei, int E, int Etot,
                                                int nb, int* __restrict__ gcur1,
                                                int2* __restrict__ pairs) {
    __shared__ int h[NB_MAX];
    __shared__ int cur[NB_MAX];
    for (int i = threadIdx.x; i < nb; i += 256) h[i] = 0;
    __syncthreads();
    int base = blockIdx.x * TILE_E;
    int lim = min(base + TILE_E, Etot);
    for (int e = base + threadIdx.x; e < lim; e += 256) {
        int d = (e < E) ? ei[E + e] : e - E;
        atomicAdd(&h[d >> BKT_SH], 1);
    }
    __syncthreads();
    for (int i = threadIdx.x; i < nb; i += 256)
        cur[i] = h[i] ? atomicAdd(&gcur1[i], h[i]) : 0;
    __syncthreads();
    for (int e = base + threadIdx.x; e < lim; e += 256) {
        int s, d;
        if (e < E) { s = ei[e]; d = ei[E + e]; } else { s = d = e - E; }
        int p = atomicAdd(&cur[d >> BKT_SH], 1);
        pairs[p] = make_int2(s, d);
    }
}

__global__ __launch_bounds__(256) void buildcsr_k(const int2* __restrict__ pairs,
                                                  const int* __restrict__ bbase,
                                                  int* __restrict__ rowptr,
                                                  int* __restrict__ cols,
                                                  int n, int etot) {
    __shared__ int cnt[BKT];
    __shared__ int part[256];
    int b = blockIdx.x;
    int d0 = b << BKT_SH;
    int nd = min(BKT, n - d0);
    int rbeg = bbase[b], rend = bbase[b + 1];
    for (int i = threadIdx.x; i < nd; i += 256) cnt[i] = 0;
    __syncthreads();
    for (int i = rbeg + threadIdx.x; i < rend; i += 256)
        atomicAdd(&cnt[pairs[i].y - d0], 1);
    __syncthreads();

    int t = threadIdx.x;
    int i4 = t * 4;
    int myv[4];
    int s0 = 0;
#pragma unroll
    for (int j = 0; j < 4; ++j) { myv[j] = (i4 + j < nd) ? cnt[i4 + j] : 0; s0 += myv[j]; }
    part[t] = s0;
    __syncthreads();
    for (int off = 1; off < 256; off <<= 1) {
        int tv = (t >= off) ? part[t - off] : 0;
        __syncthreads();
        part[t] += tv;
        __syncthreads();
    }
    int run = rbeg + part[t] - s0;
#pragma unroll
    for (int j = 0; j < 4; ++j) {
        if (i4 + j < nd) {
            rowptr[d0 + i4 + j] = run;
            cnt[i4 + j] = run;          // becomes absolute cursor
            run += myv[j];
        }
    }
    if (b == 0 && t == 0) rowptr[n] = etot;
    __syncthreads();
    for (int i = rbeg + threadIdx.x; i < rend; i += 256) {
        int2 p = pairs[i];
        int pos = atomicAdd(&cnt[p.y - d0], 1);
        cols[pos] = p.x;
    }
}

// ===== layers 0/1: fused softmax + bf16 aggregation, 16-lane group/node =====
__global__ __launch_bounds__(256) void gat128_k(
        const int* __restrict__ rp, const int* __restrict__ cols,
        const unsigned short* __restrict__ Hbf, const float* __restrict__ ssrc,
        const float* __restrict__ sdst, const float* __restrict__ bias,
        float* __restrict__ out, int n) {
    int d = (blockIdx.x * 256 + threadIdx.x) >> 4;
    if (d >= n) return;
    int l = threadIdx.x & 15;
    int head = l >> 2;
    int sub  = l & 3;
    int beg = rp[d], end = rp[d + 1];

    float sdh = sdst[(size_t)d * 4 + head];

    float m = -1e30f, den = 0.f;
    for (int i = beg + sub; i < end; i += 4) {
        int s = cols[i];
        float v = ssrc[(size_t)s * 4 + head] + sdh;
        v = (v >= 0.f) ? v : NEG_SLOPE * v;
        float nm = fmaxf(m, v);
        den = den * __expf(m - nm) + __expf(v - nm);
        m = nm;
    }
#pragma unroll
    for (int off = 1; off <= 2; off <<= 1) {
        float om = __shfl_xor(m, off, 64);
        float od = __shfl_xor(den, off, 64);
        float nm = fmaxf(m, om);
        den = den * __expf(m - nm) + od * __expf(om - nm);
        m = nm;
    }
    float r = 1.f / (den + 1e-16f);

    // phase 2: 2-way unrolled gather with dual accumulators
    float4 a0 = {0.f, 0.f, 0.f, 0.f}, a1 = {0.f, 0.f, 0.f, 0.f};
    float4 c0 = {0.f, 0.f, 0.f, 0.f}, c1 = {0.f, 0.f, 0.f, 0.f};

    auto proc = [&](int i, float4& p0, float4& p1) {
        int s = cols[i];
        float v = ssrc[(size_t)s * 4 + head] + sdh;
        v = (v >= 0.f) ? v : NEG_SLOPE * v;
        float a = __expf(v - m);
        const unsigned short* hp = Hbf + (size_t)s * 128 + l * 8;
        uint4 q = *reinterpret_cast<const uint4*>(hp);
        float f0 = __uint_as_float(q.x << 16);
        float f1 = __uint_as_float(q.x & 0xffff0000u);
        float f2 = __uint_as_float(q.y << 16);
        float f3 = __uint_as_float(q.y & 0xffff0000u);
        float f4 = __uint_as_float(q.z << 16);
        float f5 = __uint_as_float(q.z & 0xffff0000u);
        float f6 = __uint_as_float(q.w << 16);
        float f7 = __uint_as_float(q.w & 0xffff0000u);
        p0.x += a * f0; p0.y += a * f1; p0.z += a * f2; p0.w += a * f3;
        p1.x += a * f4; p1.y += a * f5; p1.z += a * f6; p1.w += a * f7;
    };

    int i = beg;
    if ((end - beg) & 1) { proc(i, a0, a1); ++i; }
    for (; i < end; i += 2) {
        proc(i,     a0, a1);
        proc(i + 1, c0, c1);
    }
    a0.x += c0.x; a0.y += c0.y; a0.z += c0.z; a0.w += c0.w;
    a1.x += c1.x; a1.y += c1.y; a1.z += c1.z; a1.w += c1.w;

    float4 b0 = *reinterpret_cast<const float4*>(bias + l * 8);
    float4 b1 = *reinterpret_cast<const float4*>(bias + l * 8 + 4);
    float4 v0, v1;
    v0.x = a0.x * r + b0.x; v0.y = a0.y * r + b0.y;
    v0.z = a0.z * r + b0.z; v0.w = a0.w * r + b0.w;
    v1.x = a1.x * r + b1.x; v1.y = a1.y * r + b1.y;
    v1.z = a1.z * r + b1.z; v1.w = a1.w * r + b1.w;
    v0.x = (v0.x > 0.f) ? v0.x : expm1f(v0.x);
    v0.y = (v0.y > 0.f) ? v0.y : expm1f(v0.y);
    v0.z = (v0.z > 0.f) ? v0.z : expm1f(v0.z);
    v0.w = (v0.w > 0.f) ? v0.w : expm1f(v0.w);
    v1.x = (v1.x > 0.f) ? v1.x : expm1f(v1.x);
    v1.y = (v1.y > 0.f) ? v1.y : expm1f(v1.y);
    v1.z = (v1.z > 0.f) ? v1.z : expm1f(v1.z);
    v1.w = (v1.w > 0.f) ? v1.w : expm1f(v1.w);
    float* op = out + (size_t)d * 128 + l * 8;
    *reinterpret_cast<float4*>(op)     = v0;
    *reinterpret_cast<float4*>(op + 4) = v1;
}

// ===== layer 2: fused softmax + bf16 aggregation + bias + log_softmax =======
__global__ __launch_bounds__(256) void gat40_k(
        const int* __restrict__ rp, const int* __restrict__ cols,
        const unsigned short* __restrict__ Hbf, const float* __restrict__ ssrc,
        const float* __restrict__ sdst, const float* __restrict__ b2,
        float* __restrict__ out, int n) {
    int d = (blockIdx.x * 256 + threadIdx.x) >> 4;
    if (d >= n) return;
    int l = threadIdx.x & 15;
    int beg = rp[d], end = rp[d + 1];
    float sd = sdst[d];

    float m = -1e30f, den = 0.f;
    for (int i = beg + l; i < end; i += 16) {
        int s = cols[i];
        float v = ssrc[s] + sd;
        v = (v >= 0.f) ? v : NEG_SLOPE * v;
        float nm = fmaxf(m, v);
        den = den * __expf(m - nm) + __expf(v - nm);
        m = nm;
    }
#pragma unroll
    for (int off = 1; off <= 8; off <<= 1) {
        float om = __shfl_xor(m, off, 64);
        float od = __shfl_xor(den, off, 64);
        float nm = fmaxf(m, om);
        den = den * __expf(m - nm) + od * __expf(om - nm);
        m = nm;
    }
    float r = 1.f / (den + 1e-16f);

    float4 acc = {0.f, 0.f, 0.f, 0.f};
    float4 acc2 = {0.f, 0.f, 0.f, 0.f};
    auto proc = [&](int i, float4& p) {
        int s = cols[i];
        float v = ssrc[s] + sd;
        v = (v >= 0.f) ? v : NEG_SLOPE * v;
        float a = __expf(v - m);
        if (l < 10) {
            uint2 q = *reinterpret_cast<const uint2*>(Hbf + (size_t)s * 40 + l * 4);
            float f0 = __uint_as_float(q.x << 16);
            float f1 = __uint_as_float(q.x & 0xffff0000u);
            float f2 = __uint_as_float(q.y << 16);
            float f3 = __uint_as_float(q.y & 0xffff0000u);
            p.x += a * f0; p.y += a * f1; p.z += a * f2; p.w += a * f3;
        }
    };
    int i = beg;
    if ((end - beg) & 1) { proc(i, acc); ++i; }
    for (; i < end; i += 2) { proc(i, acc); proc(i + 1, acc2); }
    acc.x += acc2.x; acc.y += acc2.y; acc.z += acc2.z; acc.w += acc2.w;

    float4 v4 = {0.f, 0.f, 0.f, 0.f};
    float mm = -1e30f;
    if (l < 10) {
        float4 b = *reinterpret_cast<const float4*>(b2 + l * 4);
        v4.x = acc.x * r + b.x; v4.y = acc.y * r + b.y;
        v4.z = acc.z * r + b.z; v4.w = acc.w * r + b.w;
        mm = fmaxf(fmaxf(v4.x, v4.y), fmaxf(v4.z, v4.w));
    }
    for (int off = 8; off > 0; off >>= 1) mm = fmaxf(mm, __shfl_xor(mm, off, 16));
    float ss = 0.f;
    if (l < 10)
        ss = __expf(v4.x - mm) + __expf(v4.y - mm) + __expf(v4.z - mm) + __expf(v4.w - mm);
    for (int off = 8; off > 0; off >>= 1) ss += __shfl_xor(ss, off, 16);
    float lse = mm + logf(ss);
    if (l < 10) {
        float4 o;
        o.x = v4.x - lse; o.y = v4.y - lse; o.z = v4.z - lse; o.w = v4.w - lse;
        *reinterpret_cast<float4*>(out + (size_t)d * 40 + l * 4) = o;
    }
}

static inline dim3 g1(long t) { return dim3((unsigned)((t + 255) / 256)); }

extern "C" void kernel_launch(void* const* d_in, const int* in_sizes, int n_in,
                              void* d_out, int out_size, void* d_ws, size_t ws_size,
                              hipStream_t stream) {
    const float* x      = (const float*)d_in[0];
    const int*   ei     = (const int*)d_in[1];
    const float* W0     = (const float*)d_in[2];
    const float* a_src0 = (const float*)d_in[3];
    const float* a_dst0 = (const float*)d_in[4];
    const float* b0     = (const float*)d_in[5];
    const float* W1     = (const float*)d_in[6];
    const float* a_src1 = (const float*)d_in[7];
    const float* a_dst1 = (const float*)d_in[8];
    const float* b1     = (const float*)d_in[9];
    const float* W2     = (const float*)d_in[10];
    const float* a_src2 = (const float*)d_in[11];
    const float* a_dst2 = (const float*)d_in[12];
    const float* b2     = (const float*)d_in[13];

    const int N    = in_sizes[0] / FIN;
    const int E    = in_sizes[1] / 2;
    const int Etot = E + N;
    const int NB   = (N + BKT - 1) / BKT;

    float* ws = (float*)d_ws;
    size_t o = 0;
    float* hB    = ws + o; o += (size_t)N * FIN;
    float* ssrc  = ws + o; o += (size_t)N * HEADS;
    float* sdst  = ws + o; o += (size_t)N * HEADS;
    unsigned short* Hbf = (unsigned short*)(ws + o); o += (size_t)N * FIN / 2;
    int* cnt1   = (int*)(ws + o); o += NB_MAX;
    int* bbase  = (int*)(ws + o); o += NB_MAX + 2;
    int* gcur1  = (int*)(ws + o); o += NB_MAX;
    int* rowptr = (int*)(ws + o); o += N + 1;
    int* cols   = (int*)(ws + o); o += Etot;
    int2* pairs = (int2*)(ws + o); o += (size_t)Etot * 2;
    unsigned short* Bhi0 = (unsigned short*)(ws + o); o += 4 * 8 * 64 * 8 / 2;
    unsigned short* Blo0 = (unsigned short*)(ws + o); o += 4 * 8 * 64 * 8 / 2;
    unsigned short* Bhi1 = (unsigned short*)(ws + o); o += 4 * 8 * 64 * 8 / 2;
    unsigned short* Blo1 = (unsigned short*)(ws + o); o += 4 * 8 * 64 * 8 / 2;
    unsigned short* Bhi2 = (unsigned short*)(ws + o); o += 4 * 3 * 64 * 8 / 2;
    unsigned short* Blo2 = (unsigned short*)(ws + o); o += 4 * 3 * 64 * 8 / 2;
    unsigned short* Shi0 = (unsigned short*)(ws + o); o += 4 * 64 * 8 / 2;
    unsigned short* Slo0 = (unsigned short*)(ws + o); o += 4 * 64 * 8 / 2;
    unsigned short* Shi1 = (unsigned short*)(ws + o); o += 4 * 64 * 8 / 2;
    unsigned short* Slo1 = (unsigned short*)(ws + o); o += 4 * 64 * 8 / 2;
    unsigned short* Shi2 = (unsigned short*)(ws + o); o += 4 * 64 * 8 / 2;
    unsigned short* Slo2 = (unsigned short*)(ws + o); o += 4 * 64 * 8 / 2;

    const int gemmBlocks = (N + 127) / 128;
    const int grpBlocks  = (N * 16 + 255) / 256;
    const int eTiles     = (Etot + TILE_E - 1) / TILE_E;

    // ---------------- CSR build + weight/score packing ----------------------
    hipMemsetAsync(cnt1, 0, NB_MAX * 4, stream);
    histA_k<<<eTiles, 256, 0, stream>>>(ei, E, Etot, NB, cnt1);
    packW_k<8><<<g1(4 * 8 * 64 * 8), 256, 0, stream>>>(W0, Bhi0, Blo0, 128);
    packW_k<8><<<g1(4 * 8 * 64 * 8), 256, 0, stream>>>(W1, Bhi1, Blo1, 128);
    packW_k<3><<<g1(4 * 3 * 64 * 8), 256, 0, stream>>>(W2, Bhi2, Blo2, NCLS);
    packS_k<4, HID><<<g1(4 * 64 * 8), 256, 0, stream>>>(W0, a_src0, a_dst0, Shi0, Slo0, 128);
    packS_k<4, HID><<<g1(4 * 64 * 8), 256, 0, stream>>>(W1, a_src1, a_dst1, Shi1, Slo1, 128);
    packS_k<1, NCLS><<<g1(4 * 64 * 8), 256, 0, stream>>>(W2, a_src2, a_dst2, Shi2, Slo2, NCLS);
    scanB_k<<<1, 128, 0, stream>>>(cnt1, bbase, gcur1, NB);
    placeA_k<<<eTiles, 256, 0, stream>>>(ei, E, Etot, NB, gcur1, pairs);
    buildcsr_k<<<NB, 256, 0, stream>>>(pairs, bbase, rowptr, cols, N, Etot);

    // ---------------- Layer 0 ----------------------------------------------
    gemm_fused_k<8, 4><<<gemmBlocks, 256, 0, stream>>>(x, Bhi0, Blo0, Shi0, Slo0, Hbf, ssrc, sdst, N, 128);
    gat128_k<<<grpBlocks, 256, 0, stream>>>(rowptr, cols, Hbf, ssrc, sdst, b0, hB, N);

    // ---------------- Layer 1 ----------------------------------------------
    gemm_fused_k<8, 4><<<gemmBlocks, 256, 0, stream>>>(hB, Bhi1, Blo1, Shi1, Slo1, Hbf, ssrc, sdst, N, 128);
    gat128_k<<<grpBlocks, 256, 0, stream>>>(rowptr, cols, Hbf, ssrc, sdst, b1, hB, N);

    // ---------------- Layer 2 (fused bias + log_softmax) --------------------
    gemm_fused_k<3, 1><<<gemmBlocks, 256, 0, stream>>>(hB, Bhi2, Blo2, Shi2, Slo2, Hbf, ssrc, sdst, N, NCLS);
    gat40_k<<<grpBlocks, 256, 0, stream>>>(rowptr, cols, Hbf, ssrc, sdst, b2, (float*)d_out, N);
}